// Round 18
// baseline (1740.979 us; speedup 1.0000x reference)
//
#include <hip/hip_runtime.h>
#include <hip/hip_bf16.h>
#include <math.h>

#define BB 4
#define TT 1024
#define DD 1024
#define HH 16
#define HSS 64
#define LL 8
#define VV 8192
#define FFD 4096
#define MM (BB*TT)   // 4096 rows
#define ASTR 3072    // fused qkv row stride (f16)

typedef __attribute__((ext_vector_type(8))) _Float16 f16x8;
typedef __attribute__((ext_vector_type(4))) _Float16 f16x4;
typedef __attribute__((ext_vector_type(4))) float floatx4;

// async global->LDS, 16B per lane; LDS dest is wave-uniform base + lane*16
__device__ __forceinline__ void gload_lds16(const void* g, void* l) {
  __builtin_amdgcn_global_load_lds(
      (const __attribute__((address_space(1))) void*)(uintptr_t)g,
      (__attribute__((address_space(3))) void*)(uintptr_t)l, 16, 0, 0);
}

// ---------------- embedding: h = tok[x] + pos[x] (pos indexed by TOKEN id - reference
// quirk); h stored f16 (residual stream tolerates f16; LN renormalizes)
__global__ __launch_bounds__(256) void embed_kernel(const int* __restrict__ x,
    const float* __restrict__ tok, const float* __restrict__ pos, _Float16* __restrict__ h)
{
  int i = blockIdx.x * 256 + threadIdx.x;
  int row = i >> 8;
  int c4 = i & 255;
  int id = x[row];
  float4 a = ((const float4*)(tok + (size_t)id * DD))[c4];
  float4 b = ((const float4*)(pos + (size_t)id * DD))[c4];
  f16x4 o;
  o[0] = (_Float16)(a.x + b.x); o[1] = (_Float16)(a.y + b.y);
  o[2] = (_Float16)(a.z + b.z); o[3] = (_Float16)(a.w + b.w);
  *(f16x4*)(h + (size_t)row * DD + c4 * 4) = o;
}

// ---------------- device bodies shared by fused prep ----------------
__device__ __forceinline__ void ln_body(const _Float16* __restrict__ in,
    const float* __restrict__ g, const float* __restrict__ bta,
    _Float16* __restrict__ out16, int row, int tid, float* sred)
{
  f16x4 xh = *(const f16x4*)(in + (size_t)row * DD + tid * 4);
  float x0 = (float)xh[0], x1 = (float)xh[1], x2 = (float)xh[2], x3 = (float)xh[3];
  float s = x0 + x1 + x2 + x3;
  #pragma unroll
  for (int o = 32; o; o >>= 1) s += __shfl_down(s, o);
  if ((tid & 63) == 0) sred[tid >> 6] = s;
  __syncthreads();
  float mean = (sred[0] + sred[1] + sred[2] + sred[3]) * (1.f / DD);
  float d0 = x0 - mean, d1 = x1 - mean, d2 = x2 - mean, d3 = x3 - mean;
  float sq = d0 * d0 + d1 * d1 + d2 * d2 + d3 * d3;
  #pragma unroll
  for (int o = 32; o; o >>= 1) sq += __shfl_down(sq, o);
  if ((tid & 63) == 0) sred[4 + (tid >> 6)] = sq;
  __syncthreads();
  float var = (sred[4] + sred[5] + sred[6] + sred[7]) * (1.f / DD);
  float inv = rsqrtf(var + 1e-5f);
  float4 gv = ((const float4*)g)[tid];
  float4 bv = ((const float4*)bta)[tid];
  f16x4 o16;
  o16[0] = (_Float16)(d0 * inv * gv.x + bv.x);
  o16[1] = (_Float16)(d1 * inv * gv.y + bv.y);
  o16[2] = (_Float16)(d2 * inv * gv.z + bv.z);
  o16[3] = (_Float16)(d3 * inv * gv.w + bv.w);
  *(f16x4*)(out16 + (size_t)row * DD + tid * 4) = o16;
}

__device__ __forceinline__ void tcvt_body(const float* __restrict__ in,
    _Float16* __restrict__ out, int K, int N, int bx, int by, int tid, float (*tile)[65])
{
  int bk = bx * 64, bn = by * 64;
  int r = tid >> 4, c4 = (tid & 15) << 2;
  #pragma unroll
  for (int p = 0; p < 4; ++p) {
    float4 v = *(const float4*)(in + (size_t)(bk + p * 16 + r) * N + bn + c4);
    tile[p * 16 + r][c4 + 0] = v.x; tile[p * 16 + r][c4 + 1] = v.y;
    tile[p * 16 + r][c4 + 2] = v.z; tile[p * 16 + r][c4 + 3] = v.w;
  }
  __syncthreads();
  #pragma unroll
  for (int p = 0; p < 4; ++p) {
    int n = p * 16 + r;
    f16x4 o;
    o[0] = (_Float16)tile[c4 + 0][n]; o[1] = (_Float16)tile[c4 + 1][n];
    o[2] = (_Float16)tile[c4 + 2][n]; o[3] = (_Float16)tile[c4 + 3][n];
    *(f16x4*)(out + (size_t)(bn + n) * K + bk + c4) = o;
  }
}

// ---------------- standalone transpose+cvt (LM head weight, hoisted upfront)
__global__ __launch_bounds__(256) void tcvt(const float* __restrict__ in,
    _Float16* __restrict__ out, int K, int N)
{
  __shared__ float tile[64][65];
  tcvt_body(in, out, K, N, blockIdx.x, blockIdx.y, threadIdx.x, tile);
}

// ---------------- standalone layernorm (ln2, lnf)
__global__ __launch_bounds__(256) void ln_kernel(const _Float16* __restrict__ in,
    const float* __restrict__ g, const float* __restrict__ bta, _Float16* __restrict__ out16)
{
  __shared__ float sred[8];
  ln_body(in, g, bta, out16, blockIdx.x, threadIdx.x, sred);
}

// ---------------- fused per-layer prep: ln1 + qkv weight transpose + 3 weight transposes
__global__ __launch_bounds__(256) void layer_prep(const _Float16* __restrict__ h,
    const float* __restrict__ g1, const float* __restrict__ b1v, _Float16* __restrict__ hn16,
    const float* __restrict__ wq, const float* __restrict__ wk, const float* __restrict__ wv,
    _Float16* __restrict__ wqkv_t,
    const float* __restrict__ wo, _Float16* __restrict__ wo_t,
    const float* __restrict__ w1, _Float16* __restrict__ w1_t,
    const float* __restrict__ w2, _Float16* __restrict__ w2_t)
{
  __shared__ float tile[64][65];
  __shared__ float sred[8];
  const int bid = blockIdx.x;
  const int tid = threadIdx.x;
  if (bid < 4096) {
    ln_body(h, g1, b1v, hn16, bid, tid, sred);
  } else if (bid < 4864) {
    const int b2 = bid - 4096;
    const int m  = b2 >> 8;
    const int rem = b2 & 255;
    const int hh = rem >> 4, dt = rem & 15;
    const float* src = ((m == 0) ? wq : (m == 1) ? wk : wv)
                     + (size_t)hh * DD * HSS + (size_t)(dt * 64) * HSS;
    const float scale = (m == 0) ? 0.125f : 1.0f;
    const int r = tid >> 2, cq = (tid & 3) << 4;
    #pragma unroll
    for (int p = 0; p < 4; ++p) {
      float4 v = *(const float4*)(src + (size_t)r * HSS + cq + p * 4);
      tile[r][cq + p * 4 + 0] = v.x * scale; tile[r][cq + p * 4 + 1] = v.y * scale;
      tile[r][cq + p * 4 + 2] = v.z * scale; tile[r][cq + p * 4 + 3] = v.w * scale;
    }
    __syncthreads();
    const int e = tid >> 2, dq = (tid & 3) << 4;
    _Float16* dst = wqkv_t + ((size_t)(m * 1024 + hh * 64 + e)) * DD + dt * 64 + dq;
    f16x8 o0, o1;
    #pragma unroll
    for (int j = 0; j < 8; ++j) o0[j] = (_Float16)tile[dq + j][e];
    #pragma unroll
    for (int j = 0; j < 8; ++j) o1[j] = (_Float16)tile[dq + 8 + j][e];
    *(f16x8*)dst = o0;
    *(f16x8*)(dst + 8) = o1;
  } else if (bid < 5120) {
    int b2i = bid - 4864;
    tcvt_body(wo, wo_t, DD, DD, b2i & 15, b2i >> 4, tid, tile);
  } else if (bid < 6144) {
    int b2i = bid - 5120;
    tcvt_body(w1, w1_t, DD, FFD, b2i & 15, b2i >> 4, tid, tile);
  } else {
    int b2i = bid - 6144;
    tcvt_body(w2, w2_t, FFD, DD, b2i & 63, b2i >> 6, tid, tile);
  }
}

// ---------------- v transpose: qkv16 v-part [b*T+t][2048+h*64+e] -> vt[(b*16+h)*64+e][t]
__global__ __launch_bounds__(256) void vtr_kernel(const _Float16* __restrict__ qkv16,
    _Float16* __restrict__ vt)
{
  __shared__ _Float16 tile[64][80];
  const int bh = blockIdx.x >> 4;
  const int tt = blockIdx.x & 15;
  const int b = bh >> 4, hh = bh & 15;
  const int t0 = tt * 64;
  const int tid = threadIdx.x;
  #pragma unroll
  for (int i = 0; i < 2; ++i) {
    int idx = i * 256 + tid;
    int rowt = idx >> 3, ch = idx & 7;
    f16x8 v = *(const f16x8*)(qkv16 + ((size_t)b * TT + t0 + rowt) * ASTR + 2048 + hh * 64 + ch * 8);
    *(f16x8*)&tile[rowt][ch * 8] = v;
  }
  __syncthreads();
  #pragma unroll
  for (int i = 0; i < 2; ++i) {
    int idx = i * 256 + tid;
    int e = idx & 63, c = idx >> 6;
    f16x8 o;
    #pragma unroll
    for (int j = 0; j < 8; ++j) o[j] = tile[c * 8 + j][e];
    *(f16x8*)(vt + ((size_t)bh * 64 + e) * TT + t0 + c * 8) = o;
  }
}

// ---------------- m97-style MFMA f16 GEMM, 3-deep counted-vmcnt pipeline.
// Used for N=1024 shapes: wo, w2. Stage t+2 two tiles ahead; wait leaves
// 2 tiles (12 loads for BN=64) in flight -> ~2000cy of latency cover.
#define GBM 128
#define GBK 64
template<int BN, int SWZ, bool OUT16, bool RELU, bool BIAS, bool RES>
__global__ __launch_bounds__(256) void mfma_gemm(
    const _Float16* __restrict__ A, const _Float16* __restrict__ Bt,
    const float* __restrict__ bias, const _Float16* __restrict__ res,
    void* __restrict__ Cout, int M, int N, int K)
{
  constexpr int NI = BN / 32;
  __shared__ __align__(16) _Float16 Asl[3][GBM * GBK];
  __shared__ __align__(16) _Float16 Bsl[3][BN * GBK];
  const int tid = threadIdx.x;
  const int w = tid >> 6, l = tid & 63;
  const int gx = gridDim.x, gy = gridDim.y;
  const int ihw = blockIdx.y * gx + blockIdx.x;
  const int xcd = ihw & 7, local_i = ihw >> 3;
  int bm_t, bn_t;
  if (SWZ == 0) {
    const int cpx = (gx * gy) >> 3;
    const int si = xcd * cpx + local_i;
    bm_t = si / gx; bn_t = si % gx;
  } else {
    bm_t = local_i % gy;
    bn_t = xcd * (gx >> 3) + local_i / gy;
  }
  const int bm = bm_t * GBM, bn = bn_t * BN;
  const int wr = (w >> 1) * 64, wc = (w & 1) * (NI * 16);
  const int srow = l >> 3;
  const int scol = l & 7;

  floatx4 acc[4][NI];
  #pragma unroll
  for (int mi = 0; mi < 4; ++mi)
    #pragma unroll
    for (int ni = 0; ni < NI; ++ni) acc[mi][ni] = (floatx4){0.f, 0.f, 0.f, 0.f};

  auto stage = [&](int buf, int kt) {
    const int k0 = kt * GBK;
    #pragma unroll
    for (int i = 0; i < 4; ++i) {
      int rA = w * 32 + i * 8 + srow;
      const void* gpA = (const char*)(A + (size_t)(bm + rA) * K + k0) + ((scol ^ srow) << 4);
      gload_lds16(gpA, (void*)&Asl[buf][(size_t)(w * 32 + i * 8) * GBK]);
    }
    #pragma unroll
    for (int i = 0; i < BN / 32; ++i) {
      int rB = w * (BN / 4) + i * 8 + srow;
      const void* gpB = (const char*)(Bt + (size_t)(bn + rB) * K + k0) + ((scol ^ srow) << 4);
      gload_lds16(gpB, (void*)&Bsl[buf][(size_t)(w * (BN / 4) + i * 8) * GBK]);
    }
  };

  const int NT = K / GBK;
  stage(0, 0);
  if (NT > 1) stage(1, 1);
  int cur = 0;
  for (int t = 0; t < NT; ++t) {
    if (t + 2 < NT) {
      int nb = cur + 2; if (nb >= 3) nb -= 3;
      stage(nb, t + 2);
      if constexpr (BN == 64) asm volatile("s_waitcnt vmcnt(12)" ::: "memory");
      else                    asm volatile("s_waitcnt vmcnt(16)" ::: "memory");
    } else if (t + 1 < NT) {
      if constexpr (BN == 64) asm volatile("s_waitcnt vmcnt(6)" ::: "memory");
      else                    asm volatile("s_waitcnt vmcnt(8)" ::: "memory");
    } else {
      asm volatile("s_waitcnt vmcnt(0)" ::: "memory");
    }
    __builtin_amdgcn_s_barrier();          // all waves' tile-t stages visible
    asm volatile("" ::: "memory");

    const char* ab = (const char*)&Asl[cur][0];
    const char* bb = (const char*)&Bsl[cur][0];
    #pragma unroll
    for (int kk = 0; kk < 2; ++kk) {
      const int kbyte = kk * 64 + (l >> 4) * 16;
      f16x8 af[4], bf[NI];
      #pragma unroll
      for (int mi = 0; mi < 4; ++mi) {
        int row = wr + mi * 16 + (l & 15);
        af[mi] = *(const f16x8*)(ab + row * 128 + (kbyte ^ ((row & 7) << 4)));
      }
      #pragma unroll
      for (int ni = 0; ni < NI; ++ni) {
        int row = wc + ni * 16 + (l & 15);
        bf[ni] = *(const f16x8*)(bb + row * 128 + (kbyte ^ ((row & 7) << 4)));
      }
      #pragma unroll
      for (int mi = 0; mi < 4; ++mi)
        #pragma unroll
        for (int ni = 0; ni < NI; ++ni)
          acc[mi][ni] = __builtin_amdgcn_mfma_f32_16x16x32_f16(af[mi], bf[ni], acc[mi][ni], 0, 0, 0);
    }
    __builtin_amdgcn_s_barrier();          // readers done before buf reuse
    asm volatile("" ::: "memory");
    if (++cur == 3) cur = 0;
  }

  #pragma unroll
  for (int ni = 0; ni < NI; ++ni) {
    const int col = bn + wc + ni * 16 + (l & 15);
    const float bv = BIAS ? bias[col] : 0.f;
    #pragma unroll
    for (int mi = 0; mi < 4; ++mi) {
      #pragma unroll
      for (int r = 0; r < 4; ++r) {
        const int row = bm + wr + mi * 16 + (l >> 4) * 4 + r;
        float v = acc[mi][ni][r] + bv;
        if (RELU) v = fmaxf(v, 0.f);
        if (RES) v += (float)res[(size_t)row * N + col];
        if (OUT16) ((_Float16*)Cout)[(size_t)row * N + col] = (_Float16)v;
        else       ((float*)Cout)[(size_t)row * N + col] = v;
      }
    }
  }
}

// ---------------- 256x256 MFMA GEMM, read-once fragments (qkv / w1 / LM head)
#define PBM 256
#define PBN 256
#define PBK 64
template<int SWZ, bool OUT16, bool RELU, bool BIAS, bool RES>
__global__ __launch_bounds__(512) void mfma_gemm256(
    const _Float16* __restrict__ A, const _Float16* __restrict__ Bt,
    const float* __restrict__ bias, const _Float16* __restrict__ res,
    void* __restrict__ Cout, int M, int N, int K)
{
  __shared__ __align__(16) _Float16 Asl[2][PBM * PBK];   // 2 x 32 KB
  __shared__ __align__(16) _Float16 Bsl[2][PBN * PBK];   // 2 x 32 KB
  const int tid = threadIdx.x;
  const int w = tid >> 6, l = tid & 63;
  const int wm = w >> 2, wn = w & 3;          // 2(M) x 4(N) wave grid
  const int l16 = l & 15, g16 = l >> 4;
  const int rgrp = l >> 3, chunk = l & 7;
  const int gx = gridDim.x, gy = gridDim.y;
  const int ihw = blockIdx.y * gx + blockIdx.x;
  int bm_t, bn_t;
  if (SWZ == 0) {
    const int cpx = (gx * gy) >> 3;
    const int si = (ihw & 7) * cpx + (ihw >> 3);
    bm_t = si / gx; bn_t = si % gx;
  } else {
    bn_t = ihw / gy; bm_t = ihw % gy;
  }
  const int bm = bm_t * PBM, bn = bn_t * PBN;

  floatx4 acc[8][4];
  #pragma unroll
  for (int mi = 0; mi < 8; ++mi)
    #pragma unroll
    for (int ni = 0; ni < 4; ++ni) acc[mi][ni] = (floatx4){0.f, 0.f, 0.f, 0.f};

  auto stage_half = [&](int buf, int kt, int hp) {
    const int k0 = kt * PBK;
    const int half = hp & 1;
    #pragma unroll
    for (int i = 0; i < 2; ++i) {
      const int r = half * 128 + i * 64 + w * 8 + rgrp;
      if (hp < 2) {
        const char* g = (const char*)(A + (size_t)(bm + r) * K + k0) + ((chunk ^ rgrp) << 4);
        gload_lds16(g, (void*)&Asl[buf][(size_t)(half * 128 + i * 64 + w * 8) * PBK]);
      } else {
        const char* g = (const char*)(Bt + (size_t)(bn + r) * K + k0) + ((chunk ^ rgrp) << 4);
        gload_lds16(g, (void*)&Bsl[buf][(size_t)(half * 128 + i * 64 + w * 8) * PBK]);
      }
    }
  };

  stage_half(0, 0, 0); stage_half(0, 0, 1); stage_half(0, 0, 2); stage_half(0, 0, 3);

  const int NT = K >> 6;
  for (int t = 0; t < NT; ++t) {
    const int cur = t & 1;
    if (t + 1 < NT) {
      stage_half(cur ^ 1, t + 1, 0);
      asm volatile("s_waitcnt vmcnt(2)" ::: "memory");
    } else {
      asm volatile("s_waitcnt vmcnt(0)" ::: "memory");
    }
    __builtin_amdgcn_s_barrier();
    asm volatile("" ::: "memory");
    __builtin_amdgcn_sched_barrier(0);

    const char* ab = (const char*)&Asl[cur][0];
    const char* bb = (const char*)&Bsl[cur][0];

    f16x8 bf[4][2];
    #pragma unroll
    for (int c = 0; c < 2; ++c) {
      const int kbyte = c * 64 + g16 * 16;
      #pragma unroll
      for (int ni = 0; ni < 4; ++ni) {
        int row = wn * 64 + ni * 16 + l16;
        bf[ni][c] = *(const f16x8*)(bb + row * 128 + (kbyte ^ ((row & 7) << 4)));
      }
    }
    {
      f16x8 af[4][2];
      #pragma unroll
      for (int c = 0; c < 2; ++c) {
        const int kbyte = c * 64 + g16 * 16;
        #pragma unroll
        for (int mi = 0; mi < 4; ++mi) {
          int row = wm * 128 + mi * 16 + l16;
          af[mi][c] = *(const f16x8*)(ab + row * 128 + (kbyte ^ ((row & 7) << 4)));
        }
      }
      if (t + 1 < NT) stage_half(cur ^ 1, t + 1, 1);
      __builtin_amdgcn_s_setprio(1);
      #pragma unroll
      for (int c = 0; c < 2; ++c)
        #pragma unroll
        for (int mi = 0; mi < 4; ++mi)
          #pragma unroll
          for (int ni = 0; ni < 4; ++ni)
            acc[mi][ni] = __builtin_amdgcn_mfma_f32_16x16x32_f16(af[mi][c], bf[ni][c], acc[mi][ni], 0, 0, 0);
      __builtin_amdgcn_s_setprio(0);
    }
    {
      f16x8 af[4][2];
      #pragma unroll
      for (int c = 0; c < 2; ++c) {
        const int kbyte = c * 64 + g16 * 16;
        #pragma unroll
        for (int mi = 0; mi < 4; ++mi) {
          int row = wm * 128 + 64 + mi * 16 + l16;
          af[mi][c] = *(const f16x8*)(ab + row * 128 + (kbyte ^ ((row & 7) << 4)));
        }
      }
      if (t + 1 < NT) { stage_half(cur ^ 1, t + 1, 2); stage_half(cur ^ 1, t + 1, 3); }
      __builtin_amdgcn_s_setprio(1);
      #pragma unroll
      for (int c = 0; c < 2; ++c)
        #pragma unroll
        for (int mi = 0; mi < 4; ++mi)
          #pragma unroll
          for (int ni = 0; ni < 4; ++ni)
            acc[4 + mi][ni] = __builtin_amdgcn_mfma_f32_16x16x32_f16(af[mi][c], bf[ni][c], acc[4 + mi][ni], 0, 0, 0);
      __builtin_amdgcn_s_setprio(0);
    }
    asm volatile("" ::: "memory");
    __builtin_amdgcn_sched_barrier(0);
    __builtin_amdgcn_s_barrier();
  }

  #pragma unroll
  for (int ni = 0; ni < 4; ++ni) {
    const int col = bn + wn * 64 + ni * 16 + l16;
    const float bv = BIAS ? bias[col] : 0.f;
    #pragma unroll
    for (int mi = 0; mi < 8; ++mi) {
      #pragma unroll
      for (int r = 0; r < 4; ++r) {
        const int row = bm + wm * 128 + mi * 16 + g16 * 4 + r;
        float v = acc[mi][ni][r] + bv;
        if (RELU) v = fmaxf(v, 0.f);
        if (RES) v += (float)res[(size_t)row * N + col];
        if (OUT16) ((_Float16*)Cout)[(size_t)row * N + col] = (_Float16)v;
        else       ((float*)Cout)[(size_t)row * N + col] = v;
      }
    }
  }
}

// ---------------- MFMA causal flash attention, 8-wave 128-row q-blocks,
// 3-deep triple-buffered K/V staging with counted vmcnt(4).
#define AQB 128
#define AKB 64
__global__ __launch_bounds__(512) void attn_mfma(const _Float16* __restrict__ qkv16,
    const _Float16* __restrict__ vt16, _Float16* __restrict__ op)
{
  __shared__ __align__(16) _Float16 Kb[3][AKB * HSS];    // 3 x 8 KB
  __shared__ __align__(16) _Float16 Vtb[3][AKB * HSS];   // 3 x 8 KB
  __shared__ __align__(16) _Float16 Ps[8][16 * AKB];     // 16 KB -> 64 KB total
  const int qt = 7 - (blockIdx.x & 7);
  const int bh = blockIdx.x >> 3;
  const int b  = bh >> 4;
  const int hh = bh & 15;
  const int q0 = qt * AQB;
  const int t  = threadIdx.x;
  const int w  = t >> 6, l = t & 63;
  const int l16 = l & 15, g16 = l >> 4;
  const size_t rowbase = (size_t)b * TT;
  const int hoff = hh * HSS;
  const size_t vbase = (size_t)bh * 64;
  const int rgrp = l >> 3, chunk = l & 7;

  f16x8 aq[2];
  {
    const _Float16* qrow = qkv16 + (rowbase + q0 + w * 16 + l16) * ASTR + hoff;
    aq[0] = *(const f16x8*)(qrow + g16 * 8);
    aq[1] = *(const f16x8*)(qrow + 32 + g16 * 8);
  }

  floatx4 oacc[4];
  #pragma unroll
  for (int ni = 0; ni < 4; ++ni) oacc[ni] = (floatx4){0.f, 0.f, 0.f, 0.f};
  float mrow[4], srow[4];
  #pragma unroll
  for (int r = 0; r < 4; ++r) { mrow[r] = -3.0e38f; srow[r] = 0.f; }

  auto stage = [&](int buf, int tt) {
    const int j0 = tt * AKB;
    const int rk = w * 8 + rgrp;
    const char* gK = (const char*)(qkv16 + (rowbase + j0 + rk) * ASTR + 1024 + hoff)
                   + ((chunk ^ (rk & 7)) << 4);
    gload_lds16(gK, (void*)((char*)&Kb[buf][0] + (w * 8) * 128));
    const char* gV = (const char*)(vt16 + (vbase + rk) * TT + j0)
                   + ((chunk ^ (rk & 7)) << 4);
    gload_lds16(gV, (void*)((char*)&Vtb[buf][0] + (w * 8) * 128));
  };

  const int ntiles = 2 * qt + 2;
  stage(0, 0);
  if (ntiles > 1) stage(1, 1);
  int cur = 0;
  for (int tt = 0; tt < ntiles; ++tt) {
    if (tt + 2 < ntiles) {
      int nb = cur + 2; if (nb >= 3) nb -= 3;
      stage(nb, tt + 2);
      asm volatile("s_waitcnt vmcnt(4)" ::: "memory");
    } else if (tt + 1 < ntiles) {
      asm volatile("s_waitcnt vmcnt(2)" ::: "memory");
    } else {
      asm volatile("s_waitcnt vmcnt(0)" ::: "memory");
    }
    __builtin_amdgcn_s_barrier();
    asm volatile("" ::: "memory");

    const char* kb = (const char*)&Kb[cur][0];
    const char* vb = (const char*)&Vtb[cur][0];
    const int j0 = tt * AKB;
    const int dj = j0 - q0;
    if (dj <= w * 16 + 15) {
      floatx4 sacc[4];
      #pragma unroll
      for (int ni = 0; ni < 4; ++ni) sacc[ni] = (floatx4){0.f, 0.f, 0.f, 0.f};
      #pragma unroll
      for (int c = 0; c < 2; ++c) {
        const int kbyte = c * 64 + g16 * 16;
        #pragma unroll
        for (int ni = 0; ni < 4; ++ni) {
          int row = ni * 16 + l16;
          f16x8 bf = *(const f16x8*)(kb + row * 128 + (kbyte ^ ((row & 7) << 4)));
          sacc[ni] = __builtin_amdgcn_mfma_f32_16x16x32_f16(aq[c], bf, sacc[ni], 0, 0, 0);
        }
      }
      if (tt >= 2 * qt) {
        #pragma unroll
        for (int ni = 0; ni < 4; ++ni)
          #pragma unroll
          for (int r = 0; r < 4; ++r)
            if (dj + ni * 16 + l16 > w * 16 + g16 * 4 + r) sacc[ni][r] = -3.0e38f;
      }
      #pragma unroll
      for (int r = 0; r < 4; ++r) {
        float mx = fmaxf(fmaxf(sacc[0][r], sacc[1][r]), fmaxf(sacc[2][r], sacc[3][r]));
        mx = fmaxf(mx, __shfl_xor(mx, 1));
        mx = fmaxf(mx, __shfl_xor(mx, 2));
        mx = fmaxf(mx, __shfl_xor(mx, 4));
        mx = fmaxf(mx, __shfl_xor(mx, 8));
        float mnew = fmaxf(mrow[r], mx);
        float f = __expf(mrow[r] - mnew);
        mrow[r] = mnew;
        srow[r] *= f;
        #pragma unroll
        for (int ni = 0; ni < 4; ++ni) oacc[ni][r] *= f;
      }
      #pragma unroll
      for (int ni = 0; ni < 4; ++ni)
        #pragma unroll
        for (int r = 0; r < 4; ++r)
          sacc[ni][r] = __expf(sacc[ni][r] - mrow[r]);
      #pragma unroll
      for (int r = 0; r < 4; ++r) {
        float ss = sacc[0][r] + sacc[1][r] + sacc[2][r] + sacc[3][r];
        ss += __shfl_xor(ss, 1); ss += __shfl_xor(ss, 2);
        ss += __shfl_xor(ss, 4); ss += __shfl_xor(ss, 8);
        srow[r] += ss;
      }
      char* psb = (char*)&Ps[w][0];
      #pragma unroll
      for (int ni = 0; ni < 4; ++ni)
        #pragma unroll
        for (int r = 0; r < 4; ++r) {
          int q = g16 * 4 + r;
          *(_Float16*)(psb + ((q * 128 + (ni * 16 + l16) * 2) ^ ((q & 7) << 4))) = (_Float16)sacc[ni][r];
        }
      #pragma unroll
      for (int c = 0; c < 2; ++c) {
        const int kbyte = c * 64 + g16 * 16;
        f16x8 ap = *(const f16x8*)(psb + l16 * 128 + (kbyte ^ ((l16 & 7) << 4)));
        #pragma unroll
        for (int ni = 0; ni < 4; ++ni) {
          int erow = ni * 16 + l16;
          f16x8 bv = *(const f16x8*)(vb + erow * 128 + (kbyte ^ ((erow & 7) << 4)));
          oacc[ni] = __builtin_amdgcn_mfma_f32_16x16x32_f16(ap, bv, oacc[ni], 0, 0, 0);
        }
      }
    }
    __builtin_amdgcn_s_barrier();
    asm volatile("" ::: "memory");
    if (++cur == 3) cur = 0;
  }
  #pragma unroll
  for (int r = 0; r < 4; ++r) {
    float inv = 1.f / srow[r];
    _Float16* od = op + (rowbase + q0 + w * 16 + g16 * 4 + r) * (size_t)DD + hoff;
    #pragma unroll
    for (int ni = 0; ni < 4; ++ni)
      od[ni * 16 + l16] = (_Float16)(oacc[ni][r] * inv);
  }
}

extern "C" void kernel_launch(void* const* d_in, const int* in_sizes, int n_in,
                              void* d_out, int out_size, void* d_ws, size_t ws_size,
                              hipStream_t stream)
{
  const int*   x     = (const int*)d_in[0];
  const float* tok   = (const float*)d_in[1];
  const float* pos   = (const float*)d_in[2];
  const float* wq    = (const float*)d_in[3];
  const float* wk    = (const float*)d_in[4];
  const float* wv    = (const float*)d_in[5];
  const float* w_o   = (const float*)d_in[6];
  const float* b_o   = (const float*)d_in[7];
  const float* ln1_g = (const float*)d_in[8];
  const float* ln1_b = (const float*)d_in[9];
  const float* ln2_g = (const float*)d_in[10];
  const float* ln2_b = (const float*)d_in[11];
  const float* w1    = (const float*)d_in[12];
  const float* b1    = (const float*)d_in[13];
  const float* w2    = (const float*)d_in[14];
  const float* b2    = (const float*)d_in[15];
  const float* lnf_g = (const float*)d_in[16];
  const float* lnf_b = (const float*)d_in[17];
  const float* w_lm  = (const float*)d_in[18];
  const float* b_lm  = (const float*)d_in[19];
  float* out = (float*)d_out;
  char* p = (char*)d_ws;

  const size_t MB = 1024 * 1024;
  _Float16* h16    = (_Float16*)(p);              // 8 MB (residual stream, f16)
  _Float16* hn16   = (_Float16*)(p + 16 * MB);    // 8 MB
  _Float16* qkv16  = (_Float16*)(p + 24 * MB);    // 24 MB
  _Float16* vt16   = (_Float16*)(p + 48 * MB);    // 8 MB
  _Float16* ob16   = (_Float16*)(p + 56 * MB);    // 8 MB
  _Float16* mlp16  = (_Float16*)(p + 24 * MB);    // 32 MB overlay (qkv16+vt16 dead post-attn)
  _Float16* wqkv_t = (_Float16*)(p + 64 * MB);    // 6 MB
  _Float16* wo_t   = (_Float16*)(p + 70 * MB);    // 2 MB
  _Float16* w1_t   = (_Float16*)(p + 72 * MB);    // 8 MB
  _Float16* w2_t   = (_Float16*)(p + 80 * MB);    // 8 MB
  _Float16* wlm_t  = (_Float16*)(p + 88 * MB);    // 16 MB dedicated -> 104 MB total

  // LM-head weight transpose hoisted upfront
  tcvt<<<dim3(16, 128), 256, 0, stream>>>(w_lm, wlm_t, DD, VV);
  embed_kernel<<<dim3(MM * DD / 4 / 256), 256, 0, stream>>>(x, tok, pos, h16);

  for (int l = 0; l < LL; ++l) {
    const size_t wqo = (size_t)l * HH * DD * HSS;
    layer_prep<<<dim3(7168), 256, 0, stream>>>(
        h16, ln1_g + (size_t)l * DD, ln1_b + (size_t)l * DD, hn16,
        wq + wqo, wk + wqo, wv + wqo, wqkv_t,
        w_o + wqo, wo_t,
        w1 + (size_t)l * DD * FFD, w1_t,
        w2 + (size_t)l * FFD * DD, w2_t);
    mfma_gemm256<0,true,false,false,false><<<dim3(ASTR / PBN, MM / PBM), 512, 0, stream>>>(
        hn16, wqkv_t, nullptr, nullptr, qkv16, MM, ASTR, DD);
    vtr_kernel<<<dim3(BB * HH * (TT / 64)), 256, 0, stream>>>(qkv16, vt16);
    attn_mfma<<<dim3(BB * HH * (TT / AQB)), 512, 0, stream>>>(qkv16, vt16, ob16);
    mfma_gemm<64,0,true,false,true,true><<<dim3(DD / 64, MM / GBM), 256, 0, stream>>>(
        ob16, wo_t, b_o + (size_t)l * DD, hn16, h16, MM, DD, DD);
    ln_kernel<<<MM, 256, 0, stream>>>(h16, ln2_g + (size_t)l * DD, ln2_b + (size_t)l * DD, hn16);
    mfma_gemm256<2,true,true,true,false><<<dim3(FFD / PBN, MM / PBM), 512, 0, stream>>>(
        hn16, w1_t, b1 + (size_t)l * FFD, nullptr, mlp16, MM, FFD, DD);
    mfma_gemm<64,0,true,false,true,true><<<dim3(DD / 64, MM / GBM), 256, 0, stream>>>(
        mlp16, w2_t, b2 + (size_t)l * DD, hn16, h16, MM, DD, FFD);
  }
  ln_kernel<<<MM, 256, 0, stream>>>(h16, lnf_g, lnf_b, hn16);
  mfma_gemm256<2,false,false,true,false><<<dim3(VV / PBN, MM / PBM), 512, 0, stream>>>(
      hn16, wlm_t, b_lm, nullptr, out, MM, VV, DD);
}

// Round 19
// 1695.792 us; speedup vs baseline: 1.0266x; 1.0266x over previous
//
#include <hip/hip_runtime.h>
#include <hip/hip_bf16.h>
#include <math.h>

#define BB 4
#define TT 1024
#define DD 1024
#define HH 16
#define HSS 64
#define LL 8
#define VV 8192
#define FFD 4096
#define MM (BB*TT)   // 4096 rows
#define ASTR 3072    // fused qkv row stride (f16)

typedef __attribute__((ext_vector_type(8))) _Float16 f16x8;
typedef __attribute__((ext_vector_type(4))) _Float16 f16x4;
typedef __attribute__((ext_vector_type(4))) float floatx4;

// async global->LDS, 16B per lane; LDS dest is wave-uniform base + lane*16
__device__ __forceinline__ void gload_lds16(const void* g, void* l) {
  __builtin_amdgcn_global_load_lds(
      (const __attribute__((address_space(1))) void*)(uintptr_t)g,
      (__attribute__((address_space(3))) void*)(uintptr_t)l, 16, 0, 0);
}

// ---------------- embedding: h = tok[x] + pos[x] (pos indexed by TOKEN id - reference
// quirk); h stored f16 (residual stream tolerates f16; LN renormalizes)
__global__ __launch_bounds__(256) void embed_kernel(const int* __restrict__ x,
    const float* __restrict__ tok, const float* __restrict__ pos, _Float16* __restrict__ h)
{
  int i = blockIdx.x * 256 + threadIdx.x;
  int row = i >> 8;
  int c4 = i & 255;
  int id = x[row];
  float4 a = ((const float4*)(tok + (size_t)id * DD))[c4];
  float4 b = ((const float4*)(pos + (size_t)id * DD))[c4];
  f16x4 o;
  o[0] = (_Float16)(a.x + b.x); o[1] = (_Float16)(a.y + b.y);
  o[2] = (_Float16)(a.z + b.z); o[3] = (_Float16)(a.w + b.w);
  *(f16x4*)(h + (size_t)row * DD + c4 * 4) = o;
}

// ---------------- device bodies shared by fused prep ----------------
__device__ __forceinline__ void ln_body(const _Float16* __restrict__ in,
    const float* __restrict__ g, const float* __restrict__ bta,
    _Float16* __restrict__ out16, int row, int tid, float* sred)
{
  f16x4 xh = *(const f16x4*)(in + (size_t)row * DD + tid * 4);
  float x0 = (float)xh[0], x1 = (float)xh[1], x2 = (float)xh[2], x3 = (float)xh[3];
  float s = x0 + x1 + x2 + x3;
  #pragma unroll
  for (int o = 32; o; o >>= 1) s += __shfl_down(s, o);
  if ((tid & 63) == 0) sred[tid >> 6] = s;
  __syncthreads();
  float mean = (sred[0] + sred[1] + sred[2] + sred[3]) * (1.f / DD);
  float d0 = x0 - mean, d1 = x1 - mean, d2 = x2 - mean, d3 = x3 - mean;
  float sq = d0 * d0 + d1 * d1 + d2 * d2 + d3 * d3;
  #pragma unroll
  for (int o = 32; o; o >>= 1) sq += __shfl_down(sq, o);
  if ((tid & 63) == 0) sred[4 + (tid >> 6)] = sq;
  __syncthreads();
  float var = (sred[4] + sred[5] + sred[6] + sred[7]) * (1.f / DD);
  float inv = rsqrtf(var + 1e-5f);
  float4 gv = ((const float4*)g)[tid];
  float4 bv = ((const float4*)bta)[tid];
  f16x4 o16;
  o16[0] = (_Float16)(d0 * inv * gv.x + bv.x);
  o16[1] = (_Float16)(d1 * inv * gv.y + bv.y);
  o16[2] = (_Float16)(d2 * inv * gv.z + bv.z);
  o16[3] = (_Float16)(d3 * inv * gv.w + bv.w);
  *(f16x4*)(out16 + (size_t)row * DD + tid * 4) = o16;
}

__device__ __forceinline__ void tcvt_body(const float* __restrict__ in,
    _Float16* __restrict__ out, int K, int N, int bx, int by, int tid, float (*tile)[65])
{
  int bk = bx * 64, bn = by * 64;
  int r = tid >> 4, c4 = (tid & 15) << 2;
  #pragma unroll
  for (int p = 0; p < 4; ++p) {
    float4 v = *(const float4*)(in + (size_t)(bk + p * 16 + r) * N + bn + c4);
    tile[p * 16 + r][c4 + 0] = v.x; tile[p * 16 + r][c4 + 1] = v.y;
    tile[p * 16 + r][c4 + 2] = v.z; tile[p * 16 + r][c4 + 3] = v.w;
  }
  __syncthreads();
  #pragma unroll
  for (int p = 0; p < 4; ++p) {
    int n = p * 16 + r;
    f16x4 o;
    o[0] = (_Float16)tile[c4 + 0][n]; o[1] = (_Float16)tile[c4 + 1][n];
    o[2] = (_Float16)tile[c4 + 2][n]; o[3] = (_Float16)tile[c4 + 3][n];
    *(f16x4*)(out + (size_t)(bn + n) * K + bk + c4) = o;
  }
}

// ---------------- standalone transpose+cvt (LM head weight, hoisted upfront)
__global__ __launch_bounds__(256) void tcvt(const float* __restrict__ in,
    _Float16* __restrict__ out, int K, int N)
{
  __shared__ float tile[64][65];
  tcvt_body(in, out, K, N, blockIdx.x, blockIdx.y, threadIdx.x, tile);
}

// ---------------- standalone layernorm (ln2, lnf)
__global__ __launch_bounds__(256) void ln_kernel(const _Float16* __restrict__ in,
    const float* __restrict__ g, const float* __restrict__ bta, _Float16* __restrict__ out16)
{
  __shared__ float sred[8];
  ln_body(in, g, bta, out16, blockIdx.x, threadIdx.x, sred);
}

// ---------------- fused per-layer prep: ln1 + qkv weight transpose + 3 weight transposes
__global__ __launch_bounds__(256) void layer_prep(const _Float16* __restrict__ h,
    const float* __restrict__ g1, const float* __restrict__ b1v, _Float16* __restrict__ hn16,
    const float* __restrict__ wq, const float* __restrict__ wk, const float* __restrict__ wv,
    _Float16* __restrict__ wqkv_t,
    const float* __restrict__ wo, _Float16* __restrict__ wo_t,
    const float* __restrict__ w1, _Float16* __restrict__ w1_t,
    const float* __restrict__ w2, _Float16* __restrict__ w2_t)
{
  __shared__ float tile[64][65];
  __shared__ float sred[8];
  const int bid = blockIdx.x;
  const int tid = threadIdx.x;
  if (bid < 4096) {
    ln_body(h, g1, b1v, hn16, bid, tid, sred);
  } else if (bid < 4864) {
    const int b2 = bid - 4096;
    const int m  = b2 >> 8;
    const int rem = b2 & 255;
    const int hh = rem >> 4, dt = rem & 15;
    const float* src = ((m == 0) ? wq : (m == 1) ? wk : wv)
                     + (size_t)hh * DD * HSS + (size_t)(dt * 64) * HSS;
    const float scale = (m == 0) ? 0.125f : 1.0f;
    const int r = tid >> 2, cq = (tid & 3) << 4;
    #pragma unroll
    for (int p = 0; p < 4; ++p) {
      float4 v = *(const float4*)(src + (size_t)r * HSS + cq + p * 4);
      tile[r][cq + p * 4 + 0] = v.x * scale; tile[r][cq + p * 4 + 1] = v.y * scale;
      tile[r][cq + p * 4 + 2] = v.z * scale; tile[r][cq + p * 4 + 3] = v.w * scale;
    }
    __syncthreads();
    const int e = tid >> 2, dq = (tid & 3) << 4;
    _Float16* dst = wqkv_t + ((size_t)(m * 1024 + hh * 64 + e)) * DD + dt * 64 + dq;
    f16x8 o0, o1;
    #pragma unroll
    for (int j = 0; j < 8; ++j) o0[j] = (_Float16)tile[dq + j][e];
    #pragma unroll
    for (int j = 0; j < 8; ++j) o1[j] = (_Float16)tile[dq + 8 + j][e];
    *(f16x8*)dst = o0;
    *(f16x8*)(dst + 8) = o1;
  } else if (bid < 5120) {
    int b2i = bid - 4864;
    tcvt_body(wo, wo_t, DD, DD, b2i & 15, b2i >> 4, tid, tile);
  } else if (bid < 6144) {
    int b2i = bid - 5120;
    tcvt_body(w1, w1_t, DD, FFD, b2i & 15, b2i >> 4, tid, tile);
  } else {
    int b2i = bid - 6144;
    tcvt_body(w2, w2_t, FFD, DD, b2i & 63, b2i >> 6, tid, tile);
  }
}

// ---------------- m97-style MFMA f16 GEMM with 2-deep counted-vmcnt double
// buffer (R14/R17-proven best). Used for N=1024 shapes: wo, w2.
#define GBM 128
#define GBK 64
template<int BN, int SWZ, bool OUT16, bool RELU, bool BIAS, bool RES>
__global__ __launch_bounds__(256) void mfma_gemm(
    const _Float16* __restrict__ A, const _Float16* __restrict__ Bt,
    const float* __restrict__ bias, const _Float16* __restrict__ res,
    void* __restrict__ Cout, int M, int N, int K)
{
  constexpr int NI = BN / 32;
  __shared__ __align__(16) _Float16 Asl[2][GBM * GBK];
  __shared__ __align__(16) _Float16 Bsl[2][BN * GBK];
  const int tid = threadIdx.x;
  const int w = tid >> 6, l = tid & 63;
  const int gx = gridDim.x, gy = gridDim.y;
  const int ihw = blockIdx.y * gx + blockIdx.x;
  const int xcd = ihw & 7, local_i = ihw >> 3;
  int bm_t, bn_t;
  if (SWZ == 0) {
    const int cpx = (gx * gy) >> 3;
    const int si = xcd * cpx + local_i;
    bm_t = si / gx; bn_t = si % gx;
  } else {
    bm_t = local_i % gy;
    bn_t = xcd * (gx >> 3) + local_i / gy;
  }
  const int bm = bm_t * GBM, bn = bn_t * BN;
  const int wr = (w >> 1) * 64, wc = (w & 1) * (NI * 16);
  const int srow = l >> 3;
  const int scol = l & 7;

  floatx4 acc[4][NI];
  #pragma unroll
  for (int mi = 0; mi < 4; ++mi)
    #pragma unroll
    for (int ni = 0; ni < NI; ++ni) acc[mi][ni] = (floatx4){0.f, 0.f, 0.f, 0.f};

  auto stage = [&](int buf, int kt) {
    const int k0 = kt * GBK;
    #pragma unroll
    for (int i = 0; i < 4; ++i) {
      int rA = w * 32 + i * 8 + srow;
      const void* gpA = (const char*)(A + (size_t)(bm + rA) * K + k0) + ((scol ^ srow) << 4);
      gload_lds16(gpA, (void*)&Asl[buf][(size_t)(w * 32 + i * 8) * GBK]);
    }
    #pragma unroll
    for (int i = 0; i < BN / 32; ++i) {
      int rB = w * (BN / 4) + i * 8 + srow;
      const void* gpB = (const char*)(Bt + (size_t)(bn + rB) * K + k0) + ((scol ^ srow) << 4);
      gload_lds16(gpB, (void*)&Bsl[buf][(size_t)(w * (BN / 4) + i * 8) * GBK]);
    }
  };

  stage(0, 0);
  const int NT = K / GBK;
  for (int t = 0; t < NT; ++t) {
    const int cur = t & 1;
    if (t + 1 < NT) {
      stage(cur ^ 1, t + 1);
      if constexpr (BN == 64) asm volatile("s_waitcnt vmcnt(6)" ::: "memory");
      else                    asm volatile("s_waitcnt vmcnt(8)" ::: "memory");
    } else {
      asm volatile("s_waitcnt vmcnt(0)" ::: "memory");
    }
    __builtin_amdgcn_s_barrier();
    asm volatile("" ::: "memory");

    const char* ab = (const char*)&Asl[cur][0];
    const char* bb = (const char*)&Bsl[cur][0];
    #pragma unroll
    for (int kk = 0; kk < 2; ++kk) {
      const int kbyte = kk * 64 + (l >> 4) * 16;
      f16x8 af[4], bf[NI];
      #pragma unroll
      for (int mi = 0; mi < 4; ++mi) {
        int row = wr + mi * 16 + (l & 15);
        af[mi] = *(const f16x8*)(ab + row * 128 + (kbyte ^ ((row & 7) << 4)));
      }
      #pragma unroll
      for (int ni = 0; ni < NI; ++ni) {
        int row = wc + ni * 16 + (l & 15);
        bf[ni] = *(const f16x8*)(bb + row * 128 + (kbyte ^ ((row & 7) << 4)));
      }
      #pragma unroll
      for (int mi = 0; mi < 4; ++mi)
        #pragma unroll
        for (int ni = 0; ni < NI; ++ni)
          acc[mi][ni] = __builtin_amdgcn_mfma_f32_16x16x32_f16(af[mi], bf[ni], acc[mi][ni], 0, 0, 0);
    }
    __builtin_amdgcn_s_barrier();
    asm volatile("" ::: "memory");
  }

  #pragma unroll
  for (int ni = 0; ni < NI; ++ni) {
    const int col = bn + wc + ni * 16 + (l & 15);
    const float bv = BIAS ? bias[col] : 0.f;
    #pragma unroll
    for (int mi = 0; mi < 4; ++mi) {
      #pragma unroll
      for (int r = 0; r < 4; ++r) {
        const int row = bm + wr + mi * 16 + (l >> 4) * 4 + r;
        float v = acc[mi][ni][r] + bv;
        if (RELU) v = fmaxf(v, 0.f);
        if (RES) v += (float)res[(size_t)row * N + col];
        if (OUT16) ((_Float16*)Cout)[(size_t)row * N + col] = (_Float16)v;
        else       ((float*)Cout)[(size_t)row * N + col] = v;
      }
    }
  }
}

// ---------------- 256x256 MFMA GEMM, read-once fragments (qkv / w1 / LM head)
// VOUT=1 (qkv GEMM only): blocks with bn>=2048 (the V third, block-uniform)
// write their output TRANSPOSED directly into vt16[(b*1024 + (col-2048))*TT + t]
// - fuses the old vtr kernel into the epilogue (bit-identical values: same
// f32->f16 conversion the vtr copy preserved).
#define PBM 256
#define PBN 256
#define PBK 64
template<int SWZ, int VOUT, bool OUT16, bool RELU, bool BIAS, bool RES>
__global__ __launch_bounds__(512) void mfma_gemm256(
    const _Float16* __restrict__ A, const _Float16* __restrict__ Bt,
    const float* __restrict__ bias, const _Float16* __restrict__ res,
    void* __restrict__ Cout, _Float16* __restrict__ vt, int M, int N, int K)
{
  __shared__ __align__(16) _Float16 Asl[2][PBM * PBK];   // 2 x 32 KB
  __shared__ __align__(16) _Float16 Bsl[2][PBN * PBK];   // 2 x 32 KB
  const int tid = threadIdx.x;
  const int w = tid >> 6, l = tid & 63;
  const int wm = w >> 2, wn = w & 3;          // 2(M) x 4(N) wave grid
  const int l16 = l & 15, g16 = l >> 4;
  const int rgrp = l >> 3, chunk = l & 7;
  const int gx = gridDim.x, gy = gridDim.y;
  const int ihw = blockIdx.y * gx + blockIdx.x;
  int bm_t, bn_t;
  if (SWZ == 0) {
    const int cpx = (gx * gy) >> 3;
    const int si = (ihw & 7) * cpx + (ihw >> 3);
    bm_t = si / gx; bn_t = si % gx;
  } else {
    bn_t = ihw / gy; bm_t = ihw % gy;
  }
  const int bm = bm_t * PBM, bn = bn_t * PBN;

  floatx4 acc[8][4];
  #pragma unroll
  for (int mi = 0; mi < 8; ++mi)
    #pragma unroll
    for (int ni = 0; ni < 4; ++ni) acc[mi][ni] = (floatx4){0.f, 0.f, 0.f, 0.f};

  auto stage_half = [&](int buf, int kt, int hp) {
    const int k0 = kt * PBK;
    const int half = hp & 1;
    #pragma unroll
    for (int i = 0; i < 2; ++i) {
      const int r = half * 128 + i * 64 + w * 8 + rgrp;
      if (hp < 2) {
        const char* g = (const char*)(A + (size_t)(bm + r) * K + k0) + ((chunk ^ rgrp) << 4);
        gload_lds16(g, (void*)&Asl[buf][(size_t)(half * 128 + i * 64 + w * 8) * PBK]);
      } else {
        const char* g = (const char*)(Bt + (size_t)(bn + r) * K + k0) + ((chunk ^ rgrp) << 4);
        gload_lds16(g, (void*)&Bsl[buf][(size_t)(half * 128 + i * 64 + w * 8) * PBK]);
      }
    }
  };

  stage_half(0, 0, 0); stage_half(0, 0, 1); stage_half(0, 0, 2); stage_half(0, 0, 3);

  const int NT = K >> 6;
  for (int t = 0; t < NT; ++t) {
    const int cur = t & 1;
    if (t + 1 < NT) {
      stage_half(cur ^ 1, t + 1, 0);
      asm volatile("s_waitcnt vmcnt(2)" ::: "memory");
    } else {
      asm volatile("s_waitcnt vmcnt(0)" ::: "memory");
    }
    __builtin_amdgcn_s_barrier();
    asm volatile("" ::: "memory");
    __builtin_amdgcn_sched_barrier(0);

    const char* ab = (const char*)&Asl[cur][0];
    const char* bb = (const char*)&Bsl[cur][0];

    f16x8 bf[4][2];
    #pragma unroll
    for (int c = 0; c < 2; ++c) {
      const int kbyte = c * 64 + g16 * 16;
      #pragma unroll
      for (int ni = 0; ni < 4; ++ni) {
        int row = wn * 64 + ni * 16 + l16;
        bf[ni][c] = *(const f16x8*)(bb + row * 128 + (kbyte ^ ((row & 7) << 4)));
      }
    }
    {
      f16x8 af[4][2];
      #pragma unroll
      for (int c = 0; c < 2; ++c) {
        const int kbyte = c * 64 + g16 * 16;
        #pragma unroll
        for (int mi = 0; mi < 4; ++mi) {
          int row = wm * 128 + mi * 16 + l16;
          af[mi][c] = *(const f16x8*)(ab + row * 128 + (kbyte ^ ((row & 7) << 4)));
        }
      }
      if (t + 1 < NT) stage_half(cur ^ 1, t + 1, 1);
      __builtin_amdgcn_s_setprio(1);
      #pragma unroll
      for (int c = 0; c < 2; ++c)
        #pragma unroll
        for (int mi = 0; mi < 4; ++mi)
          #pragma unroll
          for (int ni = 0; ni < 4; ++ni)
            acc[mi][ni] = __builtin_amdgcn_mfma_f32_16x16x32_f16(af[mi][c], bf[ni][c], acc[mi][ni], 0, 0, 0);
      __builtin_amdgcn_s_setprio(0);
    }
    {
      f16x8 af[4][2];
      #pragma unroll
      for (int c = 0; c < 2; ++c) {
        const int kbyte = c * 64 + g16 * 16;
        #pragma unroll
        for (int mi = 0; mi < 4; ++mi) {
          int row = wm * 128 + 64 + mi * 16 + l16;
          af[mi][c] = *(const f16x8*)(ab + row * 128 + (kbyte ^ ((row & 7) << 4)));
        }
      }
      if (t + 1 < NT) { stage_half(cur ^ 1, t + 1, 2); stage_half(cur ^ 1, t + 1, 3); }
      __builtin_amdgcn_s_setprio(1);
      #pragma unroll
      for (int c = 0; c < 2; ++c)
        #pragma unroll
        for (int mi = 0; mi < 4; ++mi)
          #pragma unroll
          for (int ni = 0; ni < 4; ++ni)
            acc[4 + mi][ni] = __builtin_amdgcn_mfma_f32_16x16x32_f16(af[mi][c], bf[ni][c], acc[4 + mi][ni], 0, 0, 0);
      __builtin_amdgcn_s_setprio(0);
    }
    asm volatile("" ::: "memory");
    __builtin_amdgcn_sched_barrier(0);
    __builtin_amdgcn_s_barrier();
  }

  if (VOUT && bn >= 2048) {
    // V third: write transposed into vt16. vt row = b*1024 + (col-2048);
    // per (mi,ni) the 4 acc elems are 4 consecutive t values -> one f16x4.
    const int bq = bm >> 10;                 // batch index (256-row tile within one b)
    #pragma unroll
    for (int ni = 0; ni < 4; ++ni) {
      const int ch = bn - 2048 + wn * 64 + ni * 16 + l16;
      _Float16* vcol = vt + ((size_t)(bq * 1024 + ch)) * TT;
      #pragma unroll
      for (int mi = 0; mi < 8; ++mi) {
        const int trow = (bm & 1023) + wm * 128 + mi * 16 + g16 * 4;
        f16x4 o;
        o[0] = (_Float16)acc[mi][ni][0]; o[1] = (_Float16)acc[mi][ni][1];
        o[2] = (_Float16)acc[mi][ni][2]; o[3] = (_Float16)acc[mi][ni][3];
        *(f16x4*)(vcol + trow) = o;
      }
    }
  } else {
    #pragma unroll
    for (int ni = 0; ni < 4; ++ni) {
      const int col = bn + wn * 64 + ni * 16 + l16;
      const float bv = BIAS ? bias[col] : 0.f;
      #pragma unroll
      for (int mi = 0; mi < 8; ++mi) {
        #pragma unroll
        for (int r = 0; r < 4; ++r) {
          const int row = bm + wm * 128 + mi * 16 + g16 * 4 + r;
          float v = acc[mi][ni][r] + bv;
          if (RELU) v = fmaxf(v, 0.f);
          if (RES) v += (float)res[(size_t)row * N + col];
          if (OUT16) ((_Float16*)Cout)[(size_t)row * N + col] = (_Float16)v;
          else       ((float*)Cout)[(size_t)row * N + col] = v;
        }
      }
    }
  }
}

// ---------------- MFMA causal flash attention, 8-wave 128-row q-blocks,
// 2-deep double-buffered K/V staging with counted vmcnt(2) (R17-proven best).
#define AQB 128
#define AKB 64
__global__ __launch_bounds__(512) void attn_mfma(const _Float16* __restrict__ qkv16,
    const _Float16* __restrict__ vt16, _Float16* __restrict__ op)
{
  __shared__ __align__(16) _Float16 Kb[2][AKB * HSS];    // 2 x 8 KB
  __shared__ __align__(16) _Float16 Vtb[2][AKB * HSS];   // 2 x 8 KB
  __shared__ __align__(16) _Float16 Ps[8][16 * AKB];     // 16 KB -> 48 KB total
  const int qt = 7 - (blockIdx.x & 7);
  const int bh = blockIdx.x >> 3;
  const int b  = bh >> 4;
  const int hh = bh & 15;
  const int q0 = qt * AQB;
  const int t  = threadIdx.x;
  const int w  = t >> 6, l = t & 63;
  const int l16 = l & 15, g16 = l >> 4;
  const size_t rowbase = (size_t)b * TT;
  const int hoff = hh * HSS;
  const size_t vbase = (size_t)bh * 64;
  const int rgrp = l >> 3, chunk = l & 7;

  f16x8 aq[2];
  {
    const _Float16* qrow = qkv16 + (rowbase + q0 + w * 16 + l16) * ASTR + hoff;
    aq[0] = *(const f16x8*)(qrow + g16 * 8);
    aq[1] = *(const f16x8*)(qrow + 32 + g16 * 8);
  }

  floatx4 oacc[4];
  #pragma unroll
  for (int ni = 0; ni < 4; ++ni) oacc[ni] = (floatx4){0.f, 0.f, 0.f, 0.f};
  float mrow[4], srow[4];
  #pragma unroll
  for (int r = 0; r < 4; ++r) { mrow[r] = -3.0e38f; srow[r] = 0.f; }

  auto stage = [&](int buf, int tt) {
    const int j0 = tt * AKB;
    const int rk = w * 8 + rgrp;
    const char* gK = (const char*)(qkv16 + (rowbase + j0 + rk) * ASTR + 1024 + hoff)
                   + ((chunk ^ (rk & 7)) << 4);
    gload_lds16(gK, (void*)((char*)&Kb[buf][0] + (w * 8) * 128));
    const char* gV = (const char*)(vt16 + (vbase + rk) * TT + j0)
                   + ((chunk ^ (rk & 7)) << 4);
    gload_lds16(gV, (void*)((char*)&Vtb[buf][0] + (w * 8) * 128));
  };

  const int ntiles = 2 * qt + 2;
  stage(0, 0);
  for (int tt = 0; tt < ntiles; ++tt) {
    const int cur = tt & 1;
    if (tt + 1 < ntiles) {
      stage(cur ^ 1, tt + 1);
      asm volatile("s_waitcnt vmcnt(2)" ::: "memory");
    } else {
      asm volatile("s_waitcnt vmcnt(0)" ::: "memory");
    }
    __builtin_amdgcn_s_barrier();
    asm volatile("" ::: "memory");

    const char* kb = (const char*)&Kb[cur][0];
    const char* vb = (const char*)&Vtb[cur][0];
    const int j0 = tt * AKB;
    const int dj = j0 - q0;
    if (dj <= w * 16 + 15) {
      floatx4 sacc[4];
      #pragma unroll
      for (int ni = 0; ni < 4; ++ni) sacc[ni] = (floatx4){0.f, 0.f, 0.f, 0.f};
      #pragma unroll
      for (int c = 0; c < 2; ++c) {
        const int kbyte = c * 64 + g16 * 16;
        #pragma unroll
        for (int ni = 0; ni < 4; ++ni) {
          int row = ni * 16 + l16;
          f16x8 bf = *(const f16x8*)(kb + row * 128 + (kbyte ^ ((row & 7) << 4)));
          sacc[ni] = __builtin_amdgcn_mfma_f32_16x16x32_f16(aq[c], bf, sacc[ni], 0, 0, 0);
        }
      }
      if (tt >= 2 * qt) {
        #pragma unroll
        for (int ni = 0; ni < 4; ++ni)
          #pragma unroll
          for (int r = 0; r < 4; ++r)
            if (dj + ni * 16 + l16 > w * 16 + g16 * 4 + r) sacc[ni][r] = -3.0e38f;
      }
      #pragma unroll
      for (int r = 0; r < 4; ++r) {
        float mx = fmaxf(fmaxf(sacc[0][r], sacc[1][r]), fmaxf(sacc[2][r], sacc[3][r]));
        mx = fmaxf(mx, __shfl_xor(mx, 1));
        mx = fmaxf(mx, __shfl_xor(mx, 2));
        mx = fmaxf(mx, __shfl_xor(mx, 4));
        mx = fmaxf(mx, __shfl_xor(mx, 8));
        float mnew = fmaxf(mrow[r], mx);
        float f = __expf(mrow[r] - mnew);
        mrow[r] = mnew;
        srow[r] *= f;
        #pragma unroll
        for (int ni = 0; ni < 4; ++ni) oacc[ni][r] *= f;
      }
      #pragma unroll
      for (int ni = 0; ni < 4; ++ni)
        #pragma unroll
        for (int r = 0; r < 4; ++r)
          sacc[ni][r] = __expf(sacc[ni][r] - mrow[r]);
      #pragma unroll
      for (int r = 0; r < 4; ++r) {
        float ss = sacc[0][r] + sacc[1][r] + sacc[2][r] + sacc[3][r];
        ss += __shfl_xor(ss, 1); ss += __shfl_xor(ss, 2);
        ss += __shfl_xor(ss, 4); ss += __shfl_xor(ss, 8);
        srow[r] += ss;
      }
      char* psb = (char*)&Ps[w][0];
      #pragma unroll
      for (int ni = 0; ni < 4; ++ni)
        #pragma unroll
        for (int r = 0; r < 4; ++r) {
          int q = g16 * 4 + r;
          *(_Float16*)(psb + ((q * 128 + (ni * 16 + l16) * 2) ^ ((q & 7) << 4))) = (_Float16)sacc[ni][r];
        }
      #pragma unroll
      for (int c = 0; c < 2; ++c) {
        const int kbyte = c * 64 + g16 * 16;
        f16x8 ap = *(const f16x8*)(psb + l16 * 128 + (kbyte ^ ((l16 & 7) << 4)));
        #pragma unroll
        for (int ni = 0; ni < 4; ++ni) {
          int erow = ni * 16 + l16;
          f16x8 bv = *(const f16x8*)(vb + erow * 128 + (kbyte ^ ((erow & 7) << 4)));
          oacc[ni] = __builtin_amdgcn_mfma_f32_16x16x32_f16(ap, bv, oacc[ni], 0, 0, 0);
        }
      }
    }
    __builtin_amdgcn_s_barrier();
    asm volatile("" ::: "memory");
  }
  #pragma unroll
  for (int r = 0; r < 4; ++r) {
    float inv = 1.f / srow[r];
    _Float16* od = op + (rowbase + q0 + w * 16 + g16 * 4 + r) * (size_t)DD + hoff;
    #pragma unroll
    for (int ni = 0; ni < 4; ++ni)
      od[ni * 16 + l16] = (_Float16)(oacc[ni][r] * inv);
  }
}

extern "C" void kernel_launch(void* const* d_in, const int* in_sizes, int n_in,
                              void* d_out, int out_size, void* d_ws, size_t ws_size,
                              hipStream_t stream)
{
  const int*   x     = (const int*)d_in[0];
  const float* tok   = (const float*)d_in[1];
  const float* pos   = (const float*)d_in[2];
  const float* wq    = (const float*)d_in[3];
  const float* wk    = (const float*)d_in[4];
  const float* wv    = (const float*)d_in[5];
  const float* w_o   = (const float*)d_in[6];
  const float* b_o   = (const float*)d_in[7];
  const float* ln1_g = (const float*)d_in[8];
  const float* ln1_b = (const float*)d_in[9];
  const float* ln2_g = (const float*)d_in[10];
  const float* ln2_b = (const float*)d_in[11];
  const float* w1    = (const float*)d_in[12];
  const float* b1    = (const float*)d_in[13];
  const float* w2    = (const float*)d_in[14];
  const float* b2    = (const float*)d_in[15];
  const float* lnf_g = (const float*)d_in[16];
  const float* lnf_b = (const float*)d_in[17];
  const float* w_lm  = (const float*)d_in[18];
  const float* b_lm  = (const float*)d_in[19];
  float* out = (float*)d_out;
  char* p = (char*)d_ws;

  const size_t MB = 1024 * 1024;
  _Float16* h16    = (_Float16*)(p);              // 8 MB (residual stream, f16)
  _Float16* hn16   = (_Float16*)(p + 16 * MB);    // 8 MB
  _Float16* qkv16  = (_Float16*)(p + 24 * MB);    // 24 MB (V third unused)
  _Float16* vt16   = (_Float16*)(p + 48 * MB);    // 8 MB
  _Float16* ob16   = (_Float16*)(p + 56 * MB);    // 8 MB
  _Float16* mlp16  = (_Float16*)(p + 24 * MB);    // 32 MB overlay (qkv16+vt16 dead post-attn)
  _Float16* wqkv_t = (_Float16*)(p + 64 * MB);    // 6 MB
  _Float16* wo_t   = (_Float16*)(p + 70 * MB);    // 2 MB
  _Float16* w1_t   = (_Float16*)(p + 72 * MB);    // 8 MB
  _Float16* w2_t   = (_Float16*)(p + 80 * MB);    // 8 MB
  _Float16* wlm_t  = (_Float16*)(p + 88 * MB);    // 16 MB dedicated -> 104 MB total

  // LM-head weight transpose hoisted upfront
  tcvt<<<dim3(16, 128), 256, 0, stream>>>(w_lm, wlm_t, DD, VV);
  embed_kernel<<<dim3(MM * DD / 4 / 256), 256, 0, stream>>>(x, tok, pos, h16);

  for (int l = 0; l < LL; ++l) {
    const size_t wqo = (size_t)l * HH * DD * HSS;
    layer_prep<<<dim3(7168), 256, 0, stream>>>(
        h16, ln1_g + (size_t)l * DD, ln1_b + (size_t)l * DD, hn16,
        wq + wqo, wk + wqo, wv + wqo, wqkv_t,
        w_o + wqo, wo_t,
        w1 + (size_t)l * DD * FFD, w1_t,
        w2 + (size_t)l * FFD * DD, w2_t);
    mfma_gemm256<0,1,true,false,false,false><<<dim3(ASTR / PBN, MM / PBM), 512, 0, stream>>>(
        hn16, wqkv_t, nullptr, nullptr, qkv16, vt16, MM, ASTR, DD);
    attn_mfma<<<dim3(BB * HH * (TT / AQB)), 512, 0, stream>>>(qkv16, vt16, ob16);
    mfma_gemm<64,0,true,false,true,true><<<dim3(DD / 64, MM / GBM), 256, 0, stream>>>(
        ob16, wo_t, b_o + (size_t)l * DD, hn16, h16, MM, DD, DD);
    ln_kernel<<<MM, 256, 0, stream>>>(h16, ln2_g + (size_t)l * DD, ln2_b + (size_t)l * DD, hn16);
    mfma_gemm256<2,0,true,true,true,false><<<dim3(FFD / PBN, MM / PBM), 512, 0, stream>>>(
        hn16, w1_t, b1 + (size_t)l * FFD, nullptr, mlp16, nullptr, MM, FFD, DD);
    mfma_gemm<64,0,true,false,true,true><<<dim3(DD / 64, MM / GBM), 256, 0, stream>>>(
        mlp16, w2_t, b2 + (size_t)l * DD, hn16, h16, MM, DD, FFD);
  }
  ln_kernel<<<MM, 256, 0, stream>>>(h16, lnf_g, lnf_b, hn16);
  mfma_gemm256<2,0,false,false,true,false><<<dim3(VV / PBN, MM / PBM), 512, 0, stream>>>(
      hn16, wlm_t, b_lm, nullptr, out, nullptr, MM, VV, DD);
}

// Round 20
// 1556.410 us; speedup vs baseline: 1.1186x; 1.0896x over previous
//
#include <hip/hip_runtime.h>
#include <hip/hip_bf16.h>
#include <math.h>

#define BB 4
#define TT 1024
#define DD 1024
#define HH 16
#define HSS 64
#define LL 8
#define VV 8192
#define FFD 4096
#define MM (BB*TT)   // 4096 rows
#define ASTR 3072    // fused qkv row stride (f16)

typedef __attribute__((ext_vector_type(8))) _Float16 f16x8;
typedef __attribute__((ext_vector_type(4))) _Float16 f16x4;
typedef __attribute__((ext_vector_type(4))) float floatx4;

// async global->LDS, 16B per lane; LDS dest is wave-uniform base + lane*16
__device__ __forceinline__ void gload_lds16(const void* g, void* l) {
  __builtin_amdgcn_global_load_lds(
      (const __attribute__((address_space(1))) void*)(uintptr_t)g,
      (__attribute__((address_space(3))) void*)(uintptr_t)l, 16, 0, 0);
}

// ---------------- embedding: h = tok[x] + pos[x] (pos indexed by TOKEN id - reference
// quirk); h stored f16 (residual stream tolerates f16; LN renormalizes)
__global__ __launch_bounds__(256) void embed_kernel(const int* __restrict__ x,
    const float* __restrict__ tok, const float* __restrict__ pos, _Float16* __restrict__ h)
{
  int i = blockIdx.x * 256 + threadIdx.x;
  int row = i >> 8;
  int c4 = i & 255;
  int id = x[row];
  float4 a = ((const float4*)(tok + (size_t)id * DD))[c4];
  float4 b = ((const float4*)(pos + (size_t)id * DD))[c4];
  f16x4 o;
  o[0] = (_Float16)(a.x + b.x); o[1] = (_Float16)(a.y + b.y);
  o[2] = (_Float16)(a.z + b.z); o[3] = (_Float16)(a.w + b.w);
  *(f16x4*)(h + (size_t)row * DD + c4 * 4) = o;
}

// ---------------- device bodies shared by fused prep ----------------
__device__ __forceinline__ void ln_body(const _Float16* __restrict__ in,
    const float* __restrict__ g, const float* __restrict__ bta,
    _Float16* __restrict__ out16, int row, int tid, float* sred)
{
  f16x4 xh = *(const f16x4*)(in + (size_t)row * DD + tid * 4);
  float x0 = (float)xh[0], x1 = (float)xh[1], x2 = (float)xh[2], x3 = (float)xh[3];
  float s = x0 + x1 + x2 + x3;
  #pragma unroll
  for (int o = 32; o; o >>= 1) s += __shfl_down(s, o);
  if ((tid & 63) == 0) sred[tid >> 6] = s;
  __syncthreads();
  float mean = (sred[0] + sred[1] + sred[2] + sred[3]) * (1.f / DD);
  float d0 = x0 - mean, d1 = x1 - mean, d2 = x2 - mean, d3 = x3 - mean;
  float sq = d0 * d0 + d1 * d1 + d2 * d2 + d3 * d3;
  #pragma unroll
  for (int o = 32; o; o >>= 1) sq += __shfl_down(sq, o);
  if ((tid & 63) == 0) sred[4 + (tid >> 6)] = sq;
  __syncthreads();
  float var = (sred[4] + sred[5] + sred[6] + sred[7]) * (1.f / DD);
  float inv = rsqrtf(var + 1e-5f);
  float4 gv = ((const float4*)g)[tid];
  float4 bv = ((const float4*)bta)[tid];
  f16x4 o16;
  o16[0] = (_Float16)(d0 * inv * gv.x + bv.x);
  o16[1] = (_Float16)(d1 * inv * gv.y + bv.y);
  o16[2] = (_Float16)(d2 * inv * gv.z + bv.z);
  o16[3] = (_Float16)(d3 * inv * gv.w + bv.w);
  *(f16x4*)(out16 + (size_t)row * DD + tid * 4) = o16;
}

__device__ __forceinline__ void tcvt_body(const float* __restrict__ in,
    _Float16* __restrict__ out, int K, int N, int bx, int by, int tid, float (*tile)[65])
{
  int bk = bx * 64, bn = by * 64;
  int r = tid >> 4, c4 = (tid & 15) << 2;
  #pragma unroll
  for (int p = 0; p < 4; ++p) {
    float4 v = *(const float4*)(in + (size_t)(bk + p * 16 + r) * N + bn + c4);
    tile[p * 16 + r][c4 + 0] = v.x; tile[p * 16 + r][c4 + 1] = v.y;
    tile[p * 16 + r][c4 + 2] = v.z; tile[p * 16 + r][c4 + 3] = v.w;
  }
  __syncthreads();
  #pragma unroll
  for (int p = 0; p < 4; ++p) {
    int n = p * 16 + r;
    f16x4 o;
    o[0] = (_Float16)tile[c4 + 0][n]; o[1] = (_Float16)tile[c4 + 1][n];
    o[2] = (_Float16)tile[c4 + 2][n]; o[3] = (_Float16)tile[c4 + 3][n];
    *(f16x4*)(out + (size_t)(bn + n) * K + bk + c4) = o;
  }
}

// ---------------- standalone transpose+cvt (LM head weight, hoisted upfront)
__global__ __launch_bounds__(256) void tcvt(const float* __restrict__ in,
    _Float16* __restrict__ out, int K, int N)
{
  __shared__ float tile[64][65];
  tcvt_body(in, out, K, N, blockIdx.x, blockIdx.y, threadIdx.x, tile);
}

// ---------------- standalone layernorm (ln2, lnf)
__global__ __launch_bounds__(256) void ln_kernel(const _Float16* __restrict__ in,
    const float* __restrict__ g, const float* __restrict__ bta, _Float16* __restrict__ out16)
{
  __shared__ float sred[8];
  ln_body(in, g, bta, out16, blockIdx.x, threadIdx.x, sred);
}

// ---------------- fused per-layer prep: ln1 + qkv weight transpose + 3 weight transposes
__global__ __launch_bounds__(256) void layer_prep(const _Float16* __restrict__ h,
    const float* __restrict__ g1, const float* __restrict__ b1v, _Float16* __restrict__ hn16,
    const float* __restrict__ wq, const float* __restrict__ wk, const float* __restrict__ wv,
    _Float16* __restrict__ wqkv_t,
    const float* __restrict__ wo, _Float16* __restrict__ wo_t,
    const float* __restrict__ w1, _Float16* __restrict__ w1_t,
    const float* __restrict__ w2, _Float16* __restrict__ w2_t)
{
  __shared__ float tile[64][65];
  __shared__ float sred[8];
  const int bid = blockIdx.x;
  const int tid = threadIdx.x;
  if (bid < 4096) {
    ln_body(h, g1, b1v, hn16, bid, tid, sred);
  } else if (bid < 4864) {
    const int b2 = bid - 4096;
    const int m  = b2 >> 8;
    const int rem = b2 & 255;
    const int hh = rem >> 4, dt = rem & 15;
    const float* src = ((m == 0) ? wq : (m == 1) ? wk : wv)
                     + (size_t)hh * DD * HSS + (size_t)(dt * 64) * HSS;
    const float scale = (m == 0) ? 0.125f : 1.0f;
    const int r = tid >> 2, cq = (tid & 3) << 4;
    #pragma unroll
    for (int p = 0; p < 4; ++p) {
      float4 v = *(const float4*)(src + (size_t)r * HSS + cq + p * 4);
      tile[r][cq + p * 4 + 0] = v.x * scale; tile[r][cq + p * 4 + 1] = v.y * scale;
      tile[r][cq + p * 4 + 2] = v.z * scale; tile[r][cq + p * 4 + 3] = v.w * scale;
    }
    __syncthreads();
    const int e = tid >> 2, dq = (tid & 3) << 4;
    _Float16* dst = wqkv_t + ((size_t)(m * 1024 + hh * 64 + e)) * DD + dt * 64 + dq;
    f16x8 o0, o1;
    #pragma unroll
    for (int j = 0; j < 8; ++j) o0[j] = (_Float16)tile[dq + j][e];
    #pragma unroll
    for (int j = 0; j < 8; ++j) o1[j] = (_Float16)tile[dq + 8 + j][e];
    *(f16x8*)dst = o0;
    *(f16x8*)(dst + 8) = o1;
  } else if (bid < 5120) {
    int b2i = bid - 4864;
    tcvt_body(wo, wo_t, DD, DD, b2i & 15, b2i >> 4, tid, tile);
  } else if (bid < 6144) {
    int b2i = bid - 5120;
    tcvt_body(w1, w1_t, DD, FFD, b2i & 15, b2i >> 4, tid, tile);
  } else {
    int b2i = bid - 6144;
    tcvt_body(w2, w2_t, FFD, DD, b2i & 63, b2i >> 6, tid, tile);
  }
}

// ---------------- m97-style MFMA f16 GEMM with 2-deep counted-vmcnt double
// buffer (R14/R17-proven best). Used for N=1024 shapes: wo, w2.
#define GBM 128
#define GBK 64
template<int BN, int SWZ, bool OUT16, bool RELU, bool BIAS, bool RES>
__global__ __launch_bounds__(256) void mfma_gemm(
    const _Float16* __restrict__ A, const _Float16* __restrict__ Bt,
    const float* __restrict__ bias, const _Float16* __restrict__ res,
    void* __restrict__ Cout, int M, int N, int K)
{
  constexpr int NI = BN / 32;
  __shared__ __align__(16) _Float16 Asl[2][GBM * GBK];
  __shared__ __align__(16) _Float16 Bsl[2][BN * GBK];
  const int tid = threadIdx.x;
  const int w = tid >> 6, l = tid & 63;
  const int gx = gridDim.x, gy = gridDim.y;
  const int ihw = blockIdx.y * gx + blockIdx.x;
  const int xcd = ihw & 7, local_i = ihw >> 3;
  int bm_t, bn_t;
  if (SWZ == 0) {
    const int cpx = (gx * gy) >> 3;
    const int si = xcd * cpx + local_i;
    bm_t = si / gx; bn_t = si % gx;
  } else {
    bm_t = local_i % gy;
    bn_t = xcd * (gx >> 3) + local_i / gy;
  }
  const int bm = bm_t * GBM, bn = bn_t * BN;
  const int wr = (w >> 1) * 64, wc = (w & 1) * (NI * 16);
  const int srow = l >> 3;
  const int scol = l & 7;

  floatx4 acc[4][NI];
  #pragma unroll
  for (int mi = 0; mi < 4; ++mi)
    #pragma unroll
    for (int ni = 0; ni < NI; ++ni) acc[mi][ni] = (floatx4){0.f, 0.f, 0.f, 0.f};

  auto stage = [&](int buf, int kt) {
    const int k0 = kt * GBK;
    #pragma unroll
    for (int i = 0; i < 4; ++i) {
      int rA = w * 32 + i * 8 + srow;
      const void* gpA = (const char*)(A + (size_t)(bm + rA) * K + k0) + ((scol ^ srow) << 4);
      gload_lds16(gpA, (void*)&Asl[buf][(size_t)(w * 32 + i * 8) * GBK]);
    }
    #pragma unroll
    for (int i = 0; i < BN / 32; ++i) {
      int rB = w * (BN / 4) + i * 8 + srow;
      const void* gpB = (const char*)(Bt + (size_t)(bn + rB) * K + k0) + ((scol ^ srow) << 4);
      gload_lds16(gpB, (void*)&Bsl[buf][(size_t)(w * (BN / 4) + i * 8) * GBK]);
    }
  };

  stage(0, 0);
  const int NT = K / GBK;
  for (int t = 0; t < NT; ++t) {
    const int cur = t & 1;
    if (t + 1 < NT) {
      stage(cur ^ 1, t + 1);
      if constexpr (BN == 64) asm volatile("s_waitcnt vmcnt(6)" ::: "memory");
      else                    asm volatile("s_waitcnt vmcnt(8)" ::: "memory");
    } else {
      asm volatile("s_waitcnt vmcnt(0)" ::: "memory");
    }
    __builtin_amdgcn_s_barrier();
    asm volatile("" ::: "memory");

    const char* ab = (const char*)&Asl[cur][0];
    const char* bb = (const char*)&Bsl[cur][0];
    #pragma unroll
    for (int kk = 0; kk < 2; ++kk) {
      const int kbyte = kk * 64 + (l >> 4) * 16;
      f16x8 af[4], bf[NI];
      #pragma unroll
      for (int mi = 0; mi < 4; ++mi) {
        int row = wr + mi * 16 + (l & 15);
        af[mi] = *(const f16x8*)(ab + row * 128 + (kbyte ^ ((row & 7) << 4)));
      }
      #pragma unroll
      for (int ni = 0; ni < NI; ++ni) {
        int row = wc + ni * 16 + (l & 15);
        bf[ni] = *(const f16x8*)(bb + row * 128 + (kbyte ^ ((row & 7) << 4)));
      }
      #pragma unroll
      for (int mi = 0; mi < 4; ++mi)
        #pragma unroll
        for (int ni = 0; ni < NI; ++ni)
          acc[mi][ni] = __builtin_amdgcn_mfma_f32_16x16x32_f16(af[mi], bf[ni], acc[mi][ni], 0, 0, 0);
    }
    __builtin_amdgcn_s_barrier();
    asm volatile("" ::: "memory");
  }

  #pragma unroll
  for (int ni = 0; ni < NI; ++ni) {
    const int col = bn + wc + ni * 16 + (l & 15);
    const float bv = BIAS ? bias[col] : 0.f;
    #pragma unroll
    for (int mi = 0; mi < 4; ++mi) {
      #pragma unroll
      for (int r = 0; r < 4; ++r) {
        const int row = bm + wr + mi * 16 + (l >> 4) * 4 + r;
        float v = acc[mi][ni][r] + bv;
        if (RELU) v = fmaxf(v, 0.f);
        if (RES) v += (float)res[(size_t)row * N + col];
        if (OUT16) ((_Float16*)Cout)[(size_t)row * N + col] = (_Float16)v;
        else       ((float*)Cout)[(size_t)row * N + col] = v;
      }
    }
  }
}

// ---------------- 256x256 MFMA GEMM, read-once fragments (qkv / w1 / LM head)
// VOUT=1 (qkv GEMM only): V-third blocks write output transposed into vt16.
#define PBM 256
#define PBN 256
#define PBK 64
template<int SWZ, int VOUT, bool OUT16, bool RELU, bool BIAS, bool RES>
__global__ __launch_bounds__(512) void mfma_gemm256(
    const _Float16* __restrict__ A, const _Float16* __restrict__ Bt,
    const float* __restrict__ bias, const _Float16* __restrict__ res,
    void* __restrict__ Cout, _Float16* __restrict__ vt, int M, int N, int K)
{
  __shared__ __align__(16) _Float16 Asl[2][PBM * PBK];   // 2 x 32 KB
  __shared__ __align__(16) _Float16 Bsl[2][PBN * PBK];   // 2 x 32 KB
  const int tid = threadIdx.x;
  const int w = tid >> 6, l = tid & 63;
  const int wm = w >> 2, wn = w & 3;          // 2(M) x 4(N) wave grid
  const int l16 = l & 15, g16 = l >> 4;
  const int rgrp = l >> 3, chunk = l & 7;
  const int gx = gridDim.x, gy = gridDim.y;
  const int ihw = blockIdx.y * gx + blockIdx.x;
  int bm_t, bn_t;
  if (SWZ == 0) {
    const int cpx = (gx * gy) >> 3;
    const int si = (ihw & 7) * cpx + (ihw >> 3);
    bm_t = si / gx; bn_t = si % gx;
  } else {
    bn_t = ihw / gy; bm_t = ihw % gy;
  }
  const int bm = bm_t * PBM, bn = bn_t * PBN;

  floatx4 acc[8][4];
  #pragma unroll
  for (int mi = 0; mi < 8; ++mi)
    #pragma unroll
    for (int ni = 0; ni < 4; ++ni) acc[mi][ni] = (floatx4){0.f, 0.f, 0.f, 0.f};

  auto stage_half = [&](int buf, int kt, int hp) {
    const int k0 = kt * PBK;
    const int half = hp & 1;
    #pragma unroll
    for (int i = 0; i < 2; ++i) {
      const int r = half * 128 + i * 64 + w * 8 + rgrp;
      if (hp < 2) {
        const char* g = (const char*)(A + (size_t)(bm + r) * K + k0) + ((chunk ^ rgrp) << 4);
        gload_lds16(g, (void*)&Asl[buf][(size_t)(half * 128 + i * 64 + w * 8) * PBK]);
      } else {
        const char* g = (const char*)(Bt + (size_t)(bn + r) * K + k0) + ((chunk ^ rgrp) << 4);
        gload_lds16(g, (void*)&Bsl[buf][(size_t)(half * 128 + i * 64 + w * 8) * PBK]);
      }
    }
  };

  stage_half(0, 0, 0); stage_half(0, 0, 1); stage_half(0, 0, 2); stage_half(0, 0, 3);

  const int NT = K >> 6;
  for (int t = 0; t < NT; ++t) {
    const int cur = t & 1;
    if (t + 1 < NT) {
      stage_half(cur ^ 1, t + 1, 0);
      asm volatile("s_waitcnt vmcnt(2)" ::: "memory");
    } else {
      asm volatile("s_waitcnt vmcnt(0)" ::: "memory");
    }
    __builtin_amdgcn_s_barrier();
    asm volatile("" ::: "memory");
    __builtin_amdgcn_sched_barrier(0);

    const char* ab = (const char*)&Asl[cur][0];
    const char* bb = (const char*)&Bsl[cur][0];

    f16x8 bf[4][2];
    #pragma unroll
    for (int c = 0; c < 2; ++c) {
      const int kbyte = c * 64 + g16 * 16;
      #pragma unroll
      for (int ni = 0; ni < 4; ++ni) {
        int row = wn * 64 + ni * 16 + l16;
        bf[ni][c] = *(const f16x8*)(bb + row * 128 + (kbyte ^ ((row & 7) << 4)));
      }
    }
    {
      f16x8 af[4][2];
      #pragma unroll
      for (int c = 0; c < 2; ++c) {
        const int kbyte = c * 64 + g16 * 16;
        #pragma unroll
        for (int mi = 0; mi < 4; ++mi) {
          int row = wm * 128 + mi * 16 + l16;
          af[mi][c] = *(const f16x8*)(ab + row * 128 + (kbyte ^ ((row & 7) << 4)));
        }
      }
      if (t + 1 < NT) stage_half(cur ^ 1, t + 1, 1);
      __builtin_amdgcn_s_setprio(1);
      #pragma unroll
      for (int c = 0; c < 2; ++c)
        #pragma unroll
        for (int mi = 0; mi < 4; ++mi)
          #pragma unroll
          for (int ni = 0; ni < 4; ++ni)
            acc[mi][ni] = __builtin_amdgcn_mfma_f32_16x16x32_f16(af[mi][c], bf[ni][c], acc[mi][ni], 0, 0, 0);
      __builtin_amdgcn_s_setprio(0);
    }
    {
      f16x8 af[4][2];
      #pragma unroll
      for (int c = 0; c < 2; ++c) {
        const int kbyte = c * 64 + g16 * 16;
        #pragma unroll
        for (int mi = 0; mi < 4; ++mi) {
          int row = wm * 128 + 64 + mi * 16 + l16;
          af[mi][c] = *(const f16x8*)(ab + row * 128 + (kbyte ^ ((row & 7) << 4)));
        }
      }
      if (t + 1 < NT) { stage_half(cur ^ 1, t + 1, 2); stage_half(cur ^ 1, t + 1, 3); }
      __builtin_amdgcn_s_setprio(1);
      #pragma unroll
      for (int c = 0; c < 2; ++c)
        #pragma unroll
        for (int mi = 0; mi < 4; ++mi)
          #pragma unroll
          for (int ni = 0; ni < 4; ++ni)
            acc[4 + mi][ni] = __builtin_amdgcn_mfma_f32_16x16x32_f16(af[mi][c], bf[ni][c], acc[4 + mi][ni], 0, 0, 0);
      __builtin_amdgcn_s_setprio(0);
    }
    asm volatile("" ::: "memory");
    __builtin_amdgcn_sched_barrier(0);
    __builtin_amdgcn_s_barrier();
  }

  if (VOUT && bn >= 2048) {
    const int bq = bm >> 10;
    #pragma unroll
    for (int ni = 0; ni < 4; ++ni) {
      const int ch = bn - 2048 + wn * 64 + ni * 16 + l16;
      _Float16* vcol = vt + ((size_t)(bq * 1024 + ch)) * TT;
      #pragma unroll
      for (int mi = 0; mi < 8; ++mi) {
        const int trow = (bm & 1023) + wm * 128 + mi * 16 + g16 * 4;
        f16x4 o;
        o[0] = (_Float16)acc[mi][ni][0]; o[1] = (_Float16)acc[mi][ni][1];
        o[2] = (_Float16)acc[mi][ni][2]; o[3] = (_Float16)acc[mi][ni][3];
        *(f16x4*)(vcol + trow) = o;
      }
    }
  } else {
    #pragma unroll
    for (int ni = 0; ni < 4; ++ni) {
      const int col = bn + wn * 64 + ni * 16 + l16;
      const float bv = BIAS ? bias[col] : 0.f;
      #pragma unroll
      for (int mi = 0; mi < 8; ++mi) {
        #pragma unroll
        for (int r = 0; r < 4; ++r) {
          const int row = bm + wm * 128 + mi * 16 + g16 * 4 + r;
          float v = acc[mi][ni][r] + bv;
          if (RELU) v = fmaxf(v, 0.f);
          if (RES) v += (float)res[(size_t)row * N + col];
          if (OUT16) ((_Float16*)Cout)[(size_t)row * N + col] = (_Float16)v;
          else       ((float*)Cout)[(size_t)row * N + col] = v;
        }
      }
    }
  }
}

// ---------------- MFMA causal flash attention, 8-wave 128-row q-blocks,
// 2-deep double-buffered K/V staging with counted vmcnt(2).
// Complementary-pair block mapping: blocks i and i+256 land on the same CU
// (round-robin over 8 XCDs x 32 CUs); map them to complementary qt so every
// CU does 18 K-tile iterations instead of up to 32 (load balance).
#define AQB 128
#define AKB 64
__global__ __launch_bounds__(512) void attn_mfma(const _Float16* __restrict__ qkv16,
    const _Float16* __restrict__ vt16, _Float16* __restrict__ op)
{
  __shared__ __align__(16) _Float16 Kb[2][AKB * HSS];    // 2 x 8 KB
  __shared__ __align__(16) _Float16 Vtb[2][AKB * HSS];   // 2 x 8 KB
  __shared__ __align__(16) _Float16 Ps[8][16 * AKB];     // 16 KB -> 48 KB total
  const int ib = blockIdx.x;
  int bh, qt;
  if (ib < 256) { bh = ib >> 2; qt = 7 - (ib & 3); }     // qt 4..7 (heavy)
  else          { int j = ib - 256; bh = j >> 2; qt = j & 3; }  // qt 0..3 (light)
  const int b  = bh >> 4;
  const int hh = bh & 15;
  const int q0 = qt * AQB;
  const int t  = threadIdx.x;
  const int w  = t >> 6, l = t & 63;
  const int l16 = l & 15, g16 = l >> 4;
  const size_t rowbase = (size_t)b * TT;
  const int hoff = hh * HSS;
  const size_t vbase = (size_t)bh * 64;
  const int rgrp = l >> 3, chunk = l & 7;

  f16x8 aq[2];
  {
    const _Float16* qrow = qkv16 + (rowbase + q0 + w * 16 + l16) * ASTR + hoff;
    aq[0] = *(const f16x8*)(qrow + g16 * 8);
    aq[1] = *(const f16x8*)(qrow + 32 + g16 * 8);
  }

  floatx4 oacc[4];
  #pragma unroll
  for (int ni = 0; ni < 4; ++ni) oacc[ni] = (floatx4){0.f, 0.f, 0.f, 0.f};
  float mrow[4], srow[4];
  #pragma unroll
  for (int r = 0; r < 4; ++r) { mrow[r] = -3.0e38f; srow[r] = 0.f; }

  auto stage = [&](int buf, int tt) {
    const int j0 = tt * AKB;
    const int rk = w * 8 + rgrp;
    const char* gK = (const char*)(qkv16 + (rowbase + j0 + rk) * ASTR + 1024 + hoff)
                   + ((chunk ^ (rk & 7)) << 4);
    gload_lds16(gK, (void*)((char*)&Kb[buf][0] + (w * 8) * 128));
    const char* gV = (const char*)(vt16 + (vbase + rk) * TT + j0)
                   + ((chunk ^ (rk & 7)) << 4);
    gload_lds16(gV, (void*)((char*)&Vtb[buf][0] + (w * 8) * 128));
  };

  const int ntiles = 2 * qt + 2;
  stage(0, 0);
  for (int tt = 0; tt < ntiles; ++tt) {
    const int cur = tt & 1;
    if (tt + 1 < ntiles) {
      stage(cur ^ 1, tt + 1);
      asm volatile("s_waitcnt vmcnt(2)" ::: "memory");
    } else {
      asm volatile("s_waitcnt vmcnt(0)" ::: "memory");
    }
    __builtin_amdgcn_s_barrier();
    asm volatile("" ::: "memory");

    const char* kb = (const char*)&Kb[cur][0];
    const char* vb = (const char*)&Vtb[cur][0];
    const int j0 = tt * AKB;
    const int dj = j0 - q0;
    if (dj <= w * 16 + 15) {
      floatx4 sacc[4];
      #pragma unroll
      for (int ni = 0; ni < 4; ++ni) sacc[ni] = (floatx4){0.f, 0.f, 0.f, 0.f};
      #pragma unroll
      for (int c = 0; c < 2; ++c) {
        const int kbyte = c * 64 + g16 * 16;
        #pragma unroll
        for (int ni = 0; ni < 4; ++ni) {
          int row = ni * 16 + l16;
          f16x8 bf = *(const f16x8*)(kb + row * 128 + (kbyte ^ ((row & 7) << 4)));
          sacc[ni] = __builtin_amdgcn_mfma_f32_16x16x32_f16(aq[c], bf, sacc[ni], 0, 0, 0);
        }
      }
      if (tt >= 2 * qt) {
        #pragma unroll
        for (int ni = 0; ni < 4; ++ni)
          #pragma unroll
          for (int r = 0; r < 4; ++r)
            if (dj + ni * 16 + l16 > w * 16 + g16 * 4 + r) sacc[ni][r] = -3.0e38f;
      }
      #pragma unroll
      for (int r = 0; r < 4; ++r) {
        float mx = fmaxf(fmaxf(sacc[0][r], sacc[1][r]), fmaxf(sacc[2][r], sacc[3][r]));
        mx = fmaxf(mx, __shfl_xor(mx, 1));
        mx = fmaxf(mx, __shfl_xor(mx, 2));
        mx = fmaxf(mx, __shfl_xor(mx, 4));
        mx = fmaxf(mx, __shfl_xor(mx, 8));
        float mnew = fmaxf(mrow[r], mx);
        float f = __expf(mrow[r] - mnew);
        mrow[r] = mnew;
        srow[r] *= f;
        #pragma unroll
        for (int ni = 0; ni < 4; ++ni) oacc[ni][r] *= f;
      }
      #pragma unroll
      for (int ni = 0; ni < 4; ++ni)
        #pragma unroll
        for (int r = 0; r < 4; ++r)
          sacc[ni][r] = __expf(sacc[ni][r] - mrow[r]);
      #pragma unroll
      for (int r = 0; r < 4; ++r) {
        float ss = sacc[0][r] + sacc[1][r] + sacc[2][r] + sacc[3][r];
        ss += __shfl_xor(ss, 1); ss += __shfl_xor(ss, 2);
        ss += __shfl_xor(ss, 4); ss += __shfl_xor(ss, 8);
        srow[r] += ss;
      }
      char* psb = (char*)&Ps[w][0];
      #pragma unroll
      for (int ni = 0; ni < 4; ++ni)
        #pragma unroll
        for (int r = 0; r < 4; ++r) {
          int q = g16 * 4 + r;
          *(_Float16*)(psb + ((q * 128 + (ni * 16 + l16) * 2) ^ ((q & 7) << 4))) = (_Float16)sacc[ni][r];
        }
      #pragma unroll
      for (int c = 0; c < 2; ++c) {
        const int kbyte = c * 64 + g16 * 16;
        f16x8 ap = *(const f16x8*)(psb + l16 * 128 + (kbyte ^ ((l16 & 7) << 4)));
        #pragma unroll
        for (int ni = 0; ni < 4; ++ni) {
          int erow = ni * 16 + l16;
          f16x8 bv = *(const f16x8*)(vb + erow * 128 + (kbyte ^ ((erow & 7) << 4)));
          oacc[ni] = __builtin_amdgcn_mfma_f32_16x16x32_f16(ap, bv, oacc[ni], 0, 0, 0);
        }
      }
    }
    __builtin_amdgcn_s_barrier();
    asm volatile("" ::: "memory");
  }
  #pragma unroll
  for (int r = 0; r < 4; ++r) {
    float inv = 1.f / srow[r];
    _Float16* od = op + (rowbase + q0 + w * 16 + g16 * 4 + r) * (size_t)DD + hoff;
    #pragma unroll
    for (int ni = 0; ni < 4; ++ni)
      od[ni * 16 + l16] = (_Float16)(oacc[ni][r] * inv);
  }
}

extern "C" void kernel_launch(void* const* d_in, const int* in_sizes, int n_in,
                              void* d_out, int out_size, void* d_ws, size_t ws_size,
                              hipStream_t stream)
{
  const int*   x     = (const int*)d_in[0];
  const float* tok   = (const float*)d_in[1];
  const float* pos   = (const float*)d_in[2];
  const float* wq    = (const float*)d_in[3];
  const float* wk    = (const float*)d_in[4];
  const float* wv    = (const float*)d_in[5];
  const float* w_o   = (const float*)d_in[6];
  const float* b_o   = (const float*)d_in[7];
  const float* ln1_g = (const float*)d_in[8];
  const float* ln1_b = (const float*)d_in[9];
  const float* ln2_g = (const float*)d_in[10];
  const float* ln2_b = (const float*)d_in[11];
  const float* w1    = (const float*)d_in[12];
  const float* b1    = (const float*)d_in[13];
  const float* w2    = (const float*)d_in[14];
  const float* b2    = (const float*)d_in[15];
  const float* lnf_g = (const float*)d_in[16];
  const float* lnf_b = (const float*)d_in[17];
  const float* w_lm  = (const float*)d_in[18];
  const float* b_lm  = (const float*)d_in[19];
  float* out = (float*)d_out;
  char* p = (char*)d_ws;

  const size_t MB = 1024 * 1024;
  _Float16* h16    = (_Float16*)(p);              // 8 MB (residual stream, f16)
  _Float16* hn16   = (_Float16*)(p + 16 * MB);    // 8 MB
  _Float16* qkv16  = (_Float16*)(p + 24 * MB);    // 24 MB (V third unused)
  _Float16* vt16   = (_Float16*)(p + 48 * MB);    // 8 MB
  _Float16* ob16   = (_Float16*)(p + 56 * MB);    // 8 MB
  _Float16* mlp16  = (_Float16*)(p + 24 * MB);    // 32 MB overlay (qkv16+vt16 dead post-attn)
  _Float16* wqkv_t = (_Float16*)(p + 64 * MB);    // 6 MB
  _Float16* wo_t   = (_Float16*)(p + 70 * MB);    // 2 MB
  _Float16* w1_t   = (_Float16*)(p + 72 * MB);    // 8 MB
  _Float16* w2_t   = (_Float16*)(p + 80 * MB);    // 8 MB
  _Float16* wlm_t  = (_Float16*)(p + 88 * MB);    // 16 MB dedicated -> 104 MB total

  // LM-head weight transpose hoisted upfront
  tcvt<<<dim3(16, 128), 256, 0, stream>>>(w_lm, wlm_t, DD, VV);
  embed_kernel<<<dim3(MM * DD / 4 / 256), 256, 0, stream>>>(x, tok, pos, h16);

  for (int l = 0; l < LL; ++l) {
    const size_t wqo = (size_t)l * HH * DD * HSS;
    layer_prep<<<dim3(7168), 256, 0, stream>>>(
        h16, ln1_g + (size_t)l * DD, ln1_b + (size_t)l * DD, hn16,
        wq + wqo, wk + wqo, wv + wqo, wqkv_t,
        w_o + wqo, wo_t,
        w1 + (size_t)l * DD * FFD, w1_t,
        w2 + (size_t)l * FFD * DD, w2_t);
    mfma_gemm256<0,1,true,false,false,false><<<dim3(ASTR / PBN, MM / PBM), 512, 0, stream>>>(
        hn16, wqkv_t, nullptr, nullptr, qkv16, vt16, MM, ASTR, DD);
    attn_mfma<<<dim3(BB * HH * (TT / AQB)), 512, 0, stream>>>(qkv16, vt16, ob16);
    mfma_gemm<64,0,true,false,true,true><<<dim3(DD / 64, MM / GBM), 256, 0, stream>>>(
        ob16, wo_t, b_o + (size_t)l * DD, hn16, h16, MM, DD, DD);
    ln_kernel<<<MM, 256, 0, stream>>>(h16, ln2_g + (size_t)l * DD, ln2_b + (size_t)l * DD, hn16);
    mfma_gemm256<2,0,true,true,true,false><<<dim3(FFD / PBN, MM / PBM), 512, 0, stream>>>(
        hn16, w1_t, b1 + (size_t)l * FFD, nullptr, mlp16, nullptr, MM, FFD, DD);
    mfma_gemm<64,0,true,false,true,true><<<dim3(DD / 64, MM / GBM), 256, 0, stream>>>(
        mlp16, w2_t, b2 + (size_t)l * DD, hn16, h16, MM, DD, FFD);
  }
  ln_kernel<<<MM, 256, 0, stream>>>(h16, lnf_g, lnf_b, hn16);
  mfma_gemm256<2,0,false,false,true,false><<<dim3(VV / PBN, MM / PBM), 512, 0, stream>>>(
      hn16, wlm_t, b_lm, nullptr, out, nullptr, MM, VV, DD);
}